// Round 9
// baseline (562.425 us; speedup 1.0000x reference)
//
#include <hip/hip_runtime.h>
#include <hip/hip_bf16.h>
#include <hip/hip_fp16.h>
#include <math.h>

// ---------------------------------------------------------------------------
// RFDN panet attention, MI355X.  Round 9:
//   - gemm2: XOR-swizzled LDS for BOTH operands (As via pre-swizzled global
//     source for global_load_lds; Bs via swizzled ds_write), exp -> exp2
//     (log2e folded into K norms; S stored in log2 domain).
//   - everything else as round 8.
// ---------------------------------------------------------------------------

#define L_TOT 7470
#define L_PAD 7680   // 64 * 120, 4 chunks of 1920
#define NCHUNK 4
#define CHUNK_TILES 30   // 64-key tiles per chunk
#define KD    256    // padded 225
#define JD    512    // padded 450 = 50*3*3
#define HW    2304   // 48*48

typedef unsigned short u16;
typedef __attribute__((ext_vector_type(8))) short bf16x8;
typedef __attribute__((ext_vector_type(4))) float f32x4;

__device__ inline u16 f2b(float f) {
    __hip_bfloat16 h = __float2bfloat16(f);
    return __builtin_bit_cast(u16, h);
}
__device__ inline float b2f(u16 u) {
    __hip_bfloat16 h = __builtin_bit_cast(__hip_bfloat16, u);
    return __bfloat162float(h);
}
__device__ inline u16 f2h(float f) {
    __half h = __float2half(f);
    return __builtin_bit_cast(u16, h);
}
__device__ inline float h2f(u16 u) {
    __half h = __builtin_bit_cast(__half, u);
    return __half2float(h);
}

__constant__ int c_hs[5]   = {48, 43, 38, 33, 28};
__constant__ int c_loff[6] = {0, 2304, 4153, 5597, 6686, 7470};

#define GLOAD16(g, l) __builtin_amdgcn_global_load_lds(                          \
        (__attribute__((address_space(1))) const void*)(g),                      \
        (__attribute__((address_space(3))) void*)(l), 16, 0, 0)

// --------------------------- prep: resize weights + decode table -----------
__global__ void prep_kernel(float* __restrict__ wmall, int* __restrict__ dtab) {
    int r = blockIdx.x * 256 + threadIdx.x;
    if (r < 142) {
        int sizes[4] = {43, 38, 33, 28};
        int si = 0, i = r, woffs = 0;
        for (si = 0; si < 4; ++si) {
            if (i < sizes[si]) break;
            i -= sizes[si];
            woffs += sizes[si] * 48;
        }
        int osz = sizes[si];
        float inv_scale = 48.0f / (float)osz;
        float kscale = inv_scale;
        float sample_f = ((float)i + 0.5f) * inv_scale - 0.5f;
        float w[48];
        float tot = 0.f;
        for (int j = 0; j < 48; ++j) {
            float t = fabsf(sample_f - (float)j) / kscale;
            float v;
            if (t >= 2.f)       v = 0.f;
            else if (t >= 1.f)  v = ((-0.5f * t + 2.5f) * t - 4.f) * t + 2.f;
            else                v = ((1.5f * t - 2.5f) * t) * t + 1.f;
            w[j] = v;
            tot += v;
        }
        float invt = 1.f / tot;
        for (int j = 0; j < 48; ++j) wmall[woffs + i * 48 + j] = w[j] * invt;
    }
    if (r < L_PAD) {
        int v;
        if (r >= L_TOT) v = (int)0x80000000u;
        else {
            int si = 0;
#pragma unroll
            for (int s = 0; s < 4; ++s)
                if (r >= c_loff[s + 1]) si = s + 1;
            int pos = r - c_loff[si];
            int hs = c_hs[si];
            int ly = pos / hs, lx = pos % hs;
            v = si | (ly << 4) | (lx << 10);
        }
        dtab[r] = v;
    }
}

// --------------------------- fused resizes ---------------------------------
__global__ void resize_h_all(const float* __restrict__ in, const float* __restrict__ wm,
                             float* __restrict__ t1, float* __restrict__ t2,
                             float* __restrict__ t3, float* __restrict__ t4) {
    int idx = blockIdx.x * 256 + threadIdx.x;
    int rem = idx, osz, woffm;
    float* tmp;
    if (rem < 200 * 43 * 48) { osz = 43; tmp = t1; woffm = 0; }
    else {
        rem -= 200 * 43 * 48;
        if (rem < 200 * 38 * 48) { osz = 38; tmp = t2; woffm = 43 * 48; }
        else {
            rem -= 200 * 38 * 48;
            if (rem < 200 * 33 * 48) { osz = 33; tmp = t3; woffm = (43 + 38) * 48; }
            else {
                rem -= 200 * 33 * 48;
                if (rem >= 200 * 28 * 48) return;
                osz = 28; tmp = t4; woffm = (43 + 38 + 33) * 48;
            }
        }
    }
    int xi = rem % 48;
    int t = rem / 48;
    int yo = t % osz;
    int bc = t / osz;
    const float* wr = wm + (size_t)(woffm + yo * 48);
    const float* ip = in + (size_t)bc * 2304 + xi;
    float s = 0.f;
#pragma unroll
    for (int yi = 0; yi < 48; ++yi) s += wr[yi] * ip[yi * 48];
    tmp[rem] = s;
}

__global__ void resize_w_all(const float* __restrict__ t1, const float* __restrict__ t2,
                             const float* __restrict__ t3, const float* __restrict__ t4,
                             const float* __restrict__ wm,
                             float* __restrict__ r1, float* __restrict__ r2,
                             float* __restrict__ r3, float* __restrict__ r4) {
    int idx = blockIdx.x * 256 + threadIdx.x;
    int rem = idx, osz, woffm;
    const float* tmp;
    float* outp;
    if (rem < 200 * 43 * 43) { osz = 43; tmp = t1; outp = r1; woffm = 0; }
    else {
        rem -= 200 * 43 * 43;
        if (rem < 200 * 38 * 38) { osz = 38; tmp = t2; outp = r2; woffm = 43 * 48; }
        else {
            rem -= 200 * 38 * 38;
            if (rem < 200 * 33 * 33) { osz = 33; tmp = t3; outp = r3; woffm = (43 + 38) * 48; }
            else {
                rem -= 200 * 33 * 33;
                if (rem >= 200 * 28 * 28) return;
                osz = 28; tmp = t4; outp = r4; woffm = (43 + 38 + 33) * 48;
            }
        }
    }
    int xo = rem % osz;
    int t = rem / osz;
    int yo = t % osz;
    int bc = t / osz;
    const float* wr = wm + (size_t)(woffm + xo * 48);
    const float* ip = tmp + ((size_t)bc * osz + yo) * 48;
    float s = 0.f;
#pragma unroll
    for (int xi = 0; xi < 48; ++xi) s += wr[xi] * ip[xi];
    outp[rem] = s;
}

// ------------- fused 1x1 convs (asm+match all scales, base at scale 0) -----
__global__ void conv_all(const float* __restrict__ x,
                         const float* __restrict__ r1, const float* __restrict__ r2,
                         const float* __restrict__ r3, const float* __restrict__ r4,
                         const float* __restrict__ w_asm, const float* __restrict__ b_asm,
                         const float* __restrict__ a_asm,
                         const float* __restrict__ w_match, const float* __restrict__ b_match,
                         const float* __restrict__ a_match,
                         const float* __restrict__ w_base, const float* __restrict__ b_base,
                         const float* __restrict__ a_base,
                         float* __restrict__ base_out, float* __restrict__ refm_out,
                         float* __restrict__ mb_out) {
    int idx = blockIdx.x * 256 + threadIdx.x;
    int rem = idx, P, loffv, NCO;
    const float* in;
    if (rem < 400 * 2304) { P = 2304; in = x; loffv = 0; NCO = 100; }
    else {
        rem -= 400 * 2304;
        if (rem < 300 * 1849) { P = 1849; in = r1; loffv = 2304; NCO = 75; }
        else {
            rem -= 300 * 1849;
            if (rem < 300 * 1444) { P = 1444; in = r2; loffv = 4153; NCO = 75; }
            else {
                rem -= 300 * 1444;
                if (rem < 300 * 1089) { P = 1089; in = r3; loffv = 5597; NCO = 75; }
                else {
                    rem -= 300 * 1089;
                    if (rem >= 300 * 784) return;
                    P = 784; in = r4; loffv = 6686; NCO = 75;
                }
            }
        }
    }
    int p = rem % P;
    int t = rem / P;
    int co = t % NCO;
    int b = t / NCO;
    const float* ip = in + (size_t)b * 50 * P + p;
    const float* wr;
    float bias, av;
    float* outp;
    if (co < 50) {
        wr = w_asm + co * 50; bias = b_asm[co]; av = a_asm[0];
        outp = base_out + (size_t)200 * loffv + ((size_t)(b * 50 + co)) * P + p;
    } else if (co < 75) {
        int cm = co - 50;
        wr = w_match + cm * 50; bias = b_match[cm]; av = a_match[0];
        outp = refm_out + (size_t)100 * loffv + ((size_t)(b * 25 + cm)) * P + p;
    } else {
        int cm = co - 75;
        wr = w_base + cm * 50; bias = b_base[cm]; av = a_base[0];
        outp = mb_out + ((size_t)(b * 25 + cm)) * P + p;
    }
    float s = bias;
#pragma unroll
    for (int ci = 0; ci < 50; ++ci) s += wr[ci] * ip[(size_t)ci * P];
    *outp = (s >= 0.f) ? s : av * s;
}

// --------------------------- builders (dtab-based) -------------------------
__global__ void q_build(const float* __restrict__ mb, u16* __restrict__ Q) {
    int idx = blockIdx.x * 256 + threadIdx.x;
    if (idx >= 4 * HW * 25) return;
    int c = idx % 25;
    int t = idx / 25;
    int p = t % HW;
    int b = t / HW;
    int y = p / 48, xx = p % 48;
    const float* rc = mb + (size_t)(b * 25 + c) * HW;
    u16 ov[9];
#pragma unroll
    for (int ky = 0; ky < 3; ++ky)
#pragma unroll
        for (int kx = 0; kx < 3; ++kx) {
            int yy = y + ky - 1, xv = xx + kx - 1;
            float v = (yy >= 0 && yy < 48 && xv >= 0 && xv < 48) ? rc[yy * 48 + xv] : 0.f;
            ov[ky * 3 + kx] = f2b(v);
        }
    u16* dst = Q + (size_t)(b * HW + p) * KD + c * 9;
#pragma unroll
    for (int r = 0; r < 9; ++r) dst[r] = ov[r];
    if (c == 24) {
        u16* z = dst + 9;
#pragma unroll
        for (int i = 0; i < 31; ++i) z[i] = 0;
    }
}

// norms carry SM_SCALE * log2(e) so scores live in the exp2 domain
__global__ void norms_kernel(const float* __restrict__ refm_all, const int* __restrict__ dtab,
                             float* __restrict__ norms) {
    int idx = blockIdx.x * 256 + threadIdx.x;
    if (idx >= 4 * L_PAD) return;
    int l = idx % L_PAD;
    int b = idx / L_PAD;
    int d = dtab[l];
    if (d < 0) return;
    int si = d & 15, ly = (d >> 4) & 63, lx = (d >> 10) & 63;
    int hs = c_hs[si], P = hs * hs;
    const float* rb = refm_all + (size_t)100 * c_loff[si] + (size_t)(b * 25) * P;
    float ss = 0.f;
    for (int c = 0; c < 25; ++c) {
        const float* rc = rb + (size_t)c * P;
#pragma unroll
        for (int ky = 0; ky < 3; ++ky)
#pragma unroll
            for (int kx = 0; kx < 3; ++kx) {
                int yy = ly + ky - 1, xv = lx + kx - 1;
                if (yy >= 0 && yy < hs && xv >= 0 && xv < hs) {
                    float v = rc[yy * hs + xv];
                    ss += v * v;
                }
            }
    }
    norms[(size_t)b * L_PAD + l] = 10.0f * 1.44269504f / fmaxf(sqrtf(ss), 1e-4f);
}

__global__ void kt_build(const float* __restrict__ refm_all, const int* __restrict__ dtab,
                         const float* __restrict__ norms, u16* __restrict__ K) {
    int idx = blockIdx.x * 256 + threadIdx.x;
    if (idx >= 4 * L_PAD * 25) return;
    int c = idx % 25;
    int t = idx / 25;
    int l = t % L_PAD;
    int b = t / L_PAD;
    u16 ov[9] = {0, 0, 0, 0, 0, 0, 0, 0, 0};
    int d = dtab[l];
    if (d >= 0) {
        int si = d & 15, ly = (d >> 4) & 63, lx = (d >> 10) & 63;
        int hs = c_hs[si], P = hs * hs;
        float nrm = norms[(size_t)b * L_PAD + l];
        const float* rc = refm_all + (size_t)100 * c_loff[si] + (size_t)(b * 25 + c) * P;
#pragma unroll
        for (int ky = 0; ky < 3; ++ky)
#pragma unroll
            for (int kx = 0; kx < 3; ++kx) {
                int yy = ly + ky - 1, xv = lx + kx - 1;
                if (yy >= 0 && yy < hs && xv >= 0 && xv < hs)
                    ov[ky * 3 + kx] = f2b(rc[yy * hs + xv] * nrm);
            }
    }
    u16* dst = K + (size_t)(b * L_PAD + l) * KD + c * 9;
#pragma unroll
    for (int r = 0; r < 9; ++r) dst[r] = ov[r];
    if (c == 24) {
        u16* z = dst + 9;
#pragma unroll
        for (int i = 0; i < 31; ++i) z[i] = 0;
    }
}

// VT: thread per (b,j,l8); j==450 is the all-ones denominator column.
__global__ void v_build(const float* __restrict__ base_all, const int* __restrict__ dtab,
                        u16* __restrict__ VT) {
    int idx = blockIdx.x * 256 + threadIdx.x;
    if (idx >= 4 * JD * (L_PAD / 8)) return;
    int l8 = idx % (L_PAD / 8);
    int t = idx / (L_PAD / 8);
    int j = t % JD;
    int b = t / JD;
    int l0 = l8 * 8;
    bf16x8 ov = (bf16x8){0, 0, 0, 0, 0, 0, 0, 0};
    if (j < 450) {
        int c = j / 9, r = j % 9, ky = r / 3, kx = r % 3;
#pragma unroll
        for (int u = 0; u < 8; ++u) {
            int d = dtab[l0 + u];
            float v = 0.f;
            if (d >= 0) {
                int si = d & 15, ly = (d >> 4) & 63, lx = (d >> 10) & 63;
                int hs = c_hs[si], P = hs * hs;
                int yy = ly + ky - 1, xv = lx + kx - 1;
                if (yy >= 0 && yy < hs && xv >= 0 && xv < hs)
                    v = base_all[(size_t)200 * c_loff[si] + (size_t)(b * 50 + c) * P + yy * hs + xv];
            }
            ov[u] = (short)f2b(v);
        }
    } else if (j == 450) {
        const u16 one = f2b(1.0f);
#pragma unroll
        for (int u = 0; u < 8; ++u)
            ov[u] = (short)(dtab[l0 + u] >= 0 ? one : 0);
    }
    *(bf16x8*)&VT[(size_t)(b * JD + j) * L_PAD + l0] = ov;
}

// --------------------------- score pass (single sweep) ---------------------
__global__ __launch_bounds__(256, 4) void attn_score(
    const u16* __restrict__ Qg, const u16* __restrict__ Kg,
    u16* __restrict__ SRg, float* __restrict__ mC) {
    __shared__ u16 smem[64 * KD];         // 32 KB
    __shared__ float sm_m[2][32];
    const int bx = blockIdx.x, by = blockIdx.y;
    const int mt = by % 72, zq = by / 72;
    const int z16 = bx + 8 * zq;
    const int b = z16 >> 2, chunk = z16 & 3;
    const int bm = mt * 32;
    const u16* Q = Qg + (size_t)b * HW * KD;
    const u16* K = Kg + (size_t)b * L_PAD * KD;
    u16* SR = SRg + (size_t)b * HW * L_PAD;
    const int tid = threadIdx.x, lane = tid & 63, wid = tid >> 6;
    const int wr = wid >> 1, wc = wid & 1;
    const int l15 = lane & 15, l16 = lane >> 4, l7 = lane & 7;
    const int r_lo = lane >> 5;
    const int u_dst = lane & 31;

    {
        const u16* qrow = Q + (size_t)(bm + wid * 8 + r_lo) * KD;
        u16* qdst = smem + (size_t)(wid * 8) * KD;
#pragma unroll
        for (int q = 0; q < 4; ++q) {
            int sw = (u_dst ^ ((q * 2 + r_lo) & 7)) * 8;
            GLOAD16(qrow + (size_t)(q * 2) * KD + sw, qdst + (q * 2) * KD);
        }
    }
    __syncthreads();
    bf16x8 qf[8];
#pragma unroll
    for (int k = 0; k < 8; ++k)
        qf[k] = *(const bf16x8*)&smem[(size_t)(wr * 16 + l15) * KD + (((k * 4 + l16) ^ l7) * 8)];
    __syncthreads();

    float mrun[4] = {-3e38f, -3e38f, -3e38f, -3e38f};
    const int t0 = chunk * CHUNK_TILES;

    for (int t = t0; t < t0 + CHUNK_TILES; ++t) {
        {
            const u16* krow = K + (size_t)(t * 64 + wid * 16 + r_lo) * KD;
            u16* kdst = smem + (size_t)(wid * 16) * KD;
#pragma unroll
            for (int q = 0; q < 8; ++q) {
                int sw = (u_dst ^ ((q * 2 + r_lo) & 7)) * 8;
                GLOAD16(krow + (size_t)(q * 2) * KD + sw, kdst + (q * 2) * KD);
            }
        }
        __syncthreads();
        f32x4 acc[2];
#pragma unroll
        for (int n = 0; n < 2; ++n) acc[n] = (f32x4){0.f, 0.f, 0.f, 0.f};
#pragma unroll
        for (int k = 0; k < 8; ++k) {
            bf16x8 bfr[2];
#pragma unroll
            for (int n = 0; n < 2; ++n)
                bfr[n] = *(const bf16x8*)&smem[(size_t)(wc * 32 + n * 16 + l15) * KD
                                               + (((k * 4 + l16) ^ l7) * 8)];
#pragma unroll
            for (int n = 0; n < 2; ++n)
                acc[n] = __builtin_amdgcn_mfma_f32_16x16x32_bf16(qf[k], bfr[n], acc[n], 0, 0, 0);
        }
        const int col0 = t * 64 + wc * 32 + l15;
        const int row0 = bm + wr * 16 + l16 * 4;
#pragma unroll
        for (int n = 0; n < 2; ++n) {
            const int col = col0 + n * 16;
            const bool vld = col < L_TOT;
#pragma unroll
            for (int r = 0; r < 4; ++r) {
                float s = acc[n][r];
                if (vld) mrun[r] = fmaxf(mrun[r], s);
                SR[(size_t)(row0 + r) * L_PAD + col] = vld ? f2h(s) : (u16)0xFC00;
            }
        }
        __syncthreads();
    }

#pragma unroll
    for (int r = 0; r < 4; ++r) {
        float mv = mrun[r];
#pragma unroll
        for (int st = 1; st <= 8; st <<= 1)
            mv = fmaxf(mv, __shfl_xor(mv, st));
        mrun[r] = mv;
    }
    if (l15 == 0) {
#pragma unroll
        for (int r = 0; r < 4; ++r)
            sm_m[wc][wr * 16 + l16 * 4 + r] = mrun[r];
    }
    __syncthreads();
    if (wc == 0 && l15 == 0) {
#pragma unroll
        for (int r = 0; r < 4; ++r) {
            int row = wr * 16 + l16 * 4 + r;
            mC[(size_t)(chunk * 4 + b) * HW + bm + row] = fmaxf(sm_m[0][row], sm_m[1][row]);
        }
    }
}

// --------------------------- GEMM2 with fused exp2, swizzled LDS -----------
// Zt_z[j][pp] = sum_l VT[j][l] * exp2(SR[pp][l] - mC[pp,chunk])
__global__ __launch_bounds__(256, 4) void gemm2_kernel(
    const u16* __restrict__ VT0, const u16* __restrict__ SR0,
    const float* __restrict__ mC, u16* __restrict__ C0) {
    __shared__ u16 As[128 * 64];
    __shared__ u16 Bs[128 * 64];
    const int bx = blockIdx.x, by = blockIdx.y;
    const int within = by % 72, zq = by / 72;
    const int mt = within & 3, nt = within >> 2;
    const int z = bx + 8 * zq;
    const int batch = z >> 2, chunk = z & 3;
    const u16* A = VT0 + (size_t)batch * JD * L_PAD + chunk * (CHUNK_TILES * 64);
    const u16* B = SR0 + (size_t)batch * HW * L_PAD + chunk * (CHUNK_TILES * 64);
    u16* C = C0 + (size_t)z * JD * HW;
    const int bm = mt * 128, bn = nt * 128;
    const int tid = threadIdx.x, lane = tid & 63, wid = tid >> 6;
    const int wr = wid >> 1, wc = wid & 1;
    const int srow = lane >> 3;           // 0..7
    const int u8 = lane & 7;              // 16B unit
    const int l15 = lane & 15, l16 = lane >> 4;
    const int swu = (u8 ^ srow) * 8;      // swizzled element offset within row

    float mrow[4];
    {
        const float* mp = mC + (size_t)(chunk * 4 + batch) * HW;
#pragma unroll
        for (int q = 0; q < 4; ++q)
            mrow[q] = mp[bn + wid * 32 + srow + q * 8];
    }

    f32x4 acc[4][4];
#pragma unroll
    for (int i = 0; i < 4; ++i)
#pragma unroll
        for (int j = 0; j < 4; ++j) acc[i][j] = (f32x4){0.f, 0.f, 0.f, 0.f};

    const u16* aGrow = A + (size_t)(bm + wid * 32 + srow) * L_PAD;   // col added per tile
    const u16* bG = B + (size_t)(bn + wid * 32 + srow) * L_PAD + u8 * 8;
    u16* aL = As + wid * 32 * 64;

    union U8 { uint4 v; u16 h[8]; };
    uint4 bv[4];
#pragma unroll
    for (int q = 0; q < 4; ++q)
        bv[q] = *(const uint4*)(bG + (size_t)q * 8 * L_PAD);
    bG += 64;

    for (int t = 0; t < CHUNK_TILES; ++t) {
        // A stage: linear LDS dest, pre-swizzled global source column
#pragma unroll
        for (int q = 0; q < 4; ++q)
            GLOAD16(aGrow + (size_t)q * 8 * L_PAD + t * 64 + swu, aL + q * 8 * 64);
        uint4 bnext[4];
        if (t < CHUNK_TILES - 1) {
#pragma unroll
            for (int q = 0; q < 4; ++q)
                bnext[q] = *(const uint4*)(bG + (size_t)q * 8 * L_PAD);
            bG += 64;
        }
        // exp2-process current B tile -> swizzled LDS write
#pragma unroll
        for (int q = 0; q < 4; ++q) {
            U8 uu; uu.v = bv[q];
            bf16x8 ob;
#pragma unroll
            for (int u = 0; u < 8; ++u) {
                float e = exp2f(h2f(uu.h[u]) - mrow[q]);
                ob[u] = (short)f2b(e);
            }
            *(bf16x8*)&Bs[(size_t)(wid * 32 + srow + q * 8) * 64 + swu] = ob;
        }
        __syncthreads();
#pragma unroll
        for (int kc = 0; kc < 64; kc += 32) {
            bf16x8 af[4], bf[4];
#pragma unroll
            for (int m = 0; m < 4; ++m)
                af[m] = *(const bf16x8*)&As[(wr * 64 + m * 16 + l15) * 64
                                            + (((kc >> 3) + l16) ^ (l15 & 7)) * 8];
#pragma unroll
            for (int n = 0; n < 4; ++n)
                bf[n] = *(const bf16x8*)&Bs[(wc * 64 + n * 16 + l15) * 64
                                            + (((kc >> 3) + l16) ^ (l15 & 7)) * 8];
#pragma unroll
            for (int m = 0; m < 4; ++m)
#pragma unroll
                for (int n = 0; n < 4; ++n)
                    acc[m][n] = __builtin_amdgcn_mfma_f32_16x16x32_bf16(af[m], bf[n], acc[m][n], 0, 0, 0);
        }
        __syncthreads();
#pragma unroll
        for (int q = 0; q < 4; ++q) bv[q] = bnext[q];
    }
    const int crow0 = bm + wr * 64 + (lane >> 4) * 4;
    const int ccol = bn + wc * 64 + l15;
#pragma unroll
    for (int m = 0; m < 4; ++m)
#pragma unroll
        for (int n = 0; n < 4; ++n)
#pragma unroll
            for (int r = 0; r < 4; ++r)
                C[(size_t)(crow0 + m * 16 + r) * HW + ccol + n * 16] = f2b(acc[m][n][r]);
}

// --------------------------- combine chunk stats (after GEMM2) -------------
__global__ void combine_stats(const float* __restrict__ mC, const u16* __restrict__ Zt,
                              float* __restrict__ fac) {
    int idx = blockIdx.x * 256 + threadIdx.x;
    if (idx >= 4 * HW) return;
    int b = idx / HW, p = idx % HW;
    float m[NCHUNK], d[NCHUNK];
#pragma unroll
    for (int c = 0; c < NCHUNK; ++c) {
        m[c] = mC[(size_t)(c * 4 + b) * HW + p];
        d[c] = b2f(Zt[((size_t)(b * 4 + c) * JD + 450) * HW + p]);
    }
    float mf = m[0];
#pragma unroll
    for (int c = 1; c < NCHUNK; ++c) mf = fmaxf(mf, m[c]);
    float w[NCHUNK], df = 0.f;
#pragma unroll
    for (int c = 0; c < NCHUNK; ++c) { w[c] = exp2f(m[c] - mf); df += d[c] * w[c]; }
    float inv = 1.0f / df;
#pragma unroll
    for (int c = 0; c < NCHUNK; ++c) fac[(size_t)(c * 4 + b) * HW + p] = w[c] * inv;
}

// --------------------------- chunk reduce (weighted sum over chunks) -------
__global__ void chunk_reduce(const u16* __restrict__ Zt, const float* __restrict__ fac,
                             u16* __restrict__ Zred) {
    int idx = blockIdx.x * 256 + threadIdx.x;
    int total = 4 * JD * HW / 8;
    if (idx >= total) return;
    int e8 = idx * 8;
    int pp = e8 % HW;
    int row = e8 / HW;          // row = b*JD + j
    int b = row / JD;
    float s[8] = {};
#pragma unroll
    for (int ch = 0; ch < NCHUNK; ++ch) {
        const float* fp = fac + (size_t)(ch * 4 + b) * HW + pp;
        bf16x8 zv = *(const bf16x8*)&Zt[((size_t)(b * 4 + ch) * JD + (row % JD)) * HW + pp];
#pragma unroll
        for (int u = 0; u < 8; ++u)
            s[u] += fp[u] * b2f((u16)zv[u]);
    }
    bf16x8 o;
#pragma unroll
    for (int u = 0; u < 8; ++u) o[u] = (short)f2b(s[u]);
    *(bf16x8*)&Zred[(size_t)row * HW + pp] = o;
}

// --------------------------- final: 9-tap gather + residual ----------------
__global__ void final_kernel(const u16* __restrict__ Zred, const float* __restrict__ x,
                             float* __restrict__ out) {
    int idx = blockIdx.x * 256 + threadIdx.x;
    if (idx >= 4 * 50 * HW) return;
    int p = idx % HW;
    int t = idx / HW;
    int c = t % 50;
    int b = t / 50;
    int y = p / 48, xx = p % 48;
    const u16* Zb = Zred + (size_t)b * JD * HW;
    float s = 0.f;
#pragma unroll
    for (int ky = 0; ky < 3; ++ky) {
        int yy = y + ky - 1;
        if (yy < 0 || yy >= 48) continue;
#pragma unroll
        for (int kx = 0; kx < 3; ++kx) {
            int xv = xx + kx - 1;
            if (xv < 0 || xv >= 48) continue;
            int pp = yy * 48 + xv;
            int j = c * 9 + (2 - ky) * 3 + (2 - kx);
            s += b2f(Zb[(size_t)j * HW + pp]);
        }
    }
    size_t o = ((size_t)b * 50 + c) * HW + p;
    out[o] = x[o] + 0.25f * s;
}

// ---------------------------------------------------------------------------
extern "C" void kernel_launch(void* const* d_in, const int* in_sizes, int n_in,
                              void* d_out, int out_size, void* d_ws, size_t ws_size,
                              hipStream_t stream) {
    const float* x       = (const float*)d_in[0];
    const float* w_base  = (const float*)d_in[1];
    const float* b_base  = (const float*)d_in[2];
    const float* a_base  = (const float*)d_in[3];
    const float* w_match = (const float*)d_in[4];
    const float* b_match = (const float*)d_in[5];
    const float* a_match = (const float*)d_in[6];
    const float* w_asm   = (const float*)d_in[7];
    const float* b_asm   = (const float*)d_in[8];
    const float* a_asm   = (const float*)d_in[9];
    float* out = (float*)d_out;
    float* ws = (float*)d_ws;
    (void)in_sizes; (void)n_in; (void)out_size; (void)ws_size;

    // ---- builder scratch (aliases head of SR; dead before attn_score) ----
    size_t off = 0;
    auto alloc = [&](size_t n) { size_t o = off; off += (n + 63) & ~(size_t)63; return o; };
    size_t o_wm = alloc(142 * 48);
    size_t o_dtab = alloc(L_PAD);
    size_t o_t1 = alloc((size_t)200 * 43 * 48);
    size_t o_t2 = alloc((size_t)200 * 38 * 48);
    size_t o_t3 = alloc((size_t)200 * 33 * 48);
    size_t o_t4 = alloc((size_t)200 * 28 * 48);
    size_t o_r1 = alloc((size_t)200 * 43 * 43);
    size_t o_r2 = alloc((size_t)200 * 38 * 38);
    size_t o_r3 = alloc((size_t)200 * 33 * 33);
    size_t o_r4 = alloc((size_t)200 * 28 * 28);
    size_t o_base = alloc((size_t)200 * L_TOT);
    size_t o_refm = alloc((size_t)100 * L_TOT);
    size_t o_mb = alloc((size_t)100 * HW);
    size_t o_norms = alloc((size_t)4 * L_PAD);

    // ---- persistent layout (floats) ----
    size_t o_SR = 0;                                      // fp16 [4][HW][L_PAD]
    size_t o_Q = (size_t)4 * HW * L_PAD / 2;
    size_t o_K = o_Q + (size_t)4 * HW * KD / 2;
    size_t o_VT = o_K + (size_t)4 * L_PAD * KD / 2;
    size_t o_Z = o_VT + (size_t)4 * JD * L_PAD / 2;       // bf16 [16][JD][HW]
    size_t o_mc = o_Z + (size_t)16 * JD * HW / 2;         // f32 [16][HW]
    size_t o_fac = o_mc + (size_t)16 * HW;                // f32 [16][HW]
    size_t o_zred = o_fac + (size_t)16 * HW;              // bf16 [4][JD][HW]

    u16* Qb = (u16*)(ws + o_Q);
    u16* Kb = (u16*)(ws + o_K);
    u16* VTb = (u16*)(ws + o_VT);
    u16* SRb = (u16*)(ws + o_SR);
    u16* Zb = (u16*)(ws + o_Z);
    u16* Zrb = (u16*)(ws + o_zred);
    int* dtab = (int*)(ws + o_dtab);

    // ---- prep ----
    prep_kernel<<<(L_PAD + 255) / 256, 256, 0, stream>>>(ws + o_wm, dtab);
    // ---- resizes ----
    {
        int n = 200 * 48 * (43 + 38 + 33 + 28);
        resize_h_all<<<(n + 255) / 256, 256, 0, stream>>>(x, ws + o_wm, ws + o_t1,
                                                          ws + o_t2, ws + o_t3, ws + o_t4);
    }
    {
        int n = 200 * (43 * 43 + 38 * 38 + 33 * 33 + 28 * 28);
        resize_w_all<<<(n + 255) / 256, 256, 0, stream>>>(ws + o_t1, ws + o_t2, ws + o_t3,
                                                          ws + o_t4, ws + o_wm, ws + o_r1,
                                                          ws + o_r2, ws + o_r3, ws + o_r4);
    }
    // ---- convs ----
    {
        int n = 400 * 2304 + 300 * (1849 + 1444 + 1089 + 784);
        conv_all<<<(n + 255) / 256, 256, 0, stream>>>(
            x, ws + o_r1, ws + o_r2, ws + o_r3, ws + o_r4,
            w_asm, b_asm, a_asm, w_match, b_match, a_match, w_base, b_base, a_base,
            ws + o_base, ws + o_refm, ws + o_mb);
    }
    // ---- operand builders ----
    {
        int n = 4 * HW * 25;
        q_build<<<(n + 255) / 256, 256, 0, stream>>>(ws + o_mb, Qb);
    }
    {
        int n = 4 * L_PAD;
        norms_kernel<<<(n + 255) / 256, 256, 0, stream>>>(ws + o_refm, dtab, ws + o_norms);
    }
    {
        int n = 4 * L_PAD * 25;
        kt_build<<<(n + 255) / 256, 256, 0, stream>>>(ws + o_refm, dtab, ws + o_norms, Kb);
    }
    {
        int n = 4 * JD * (L_PAD / 8);
        v_build<<<(n + 255) / 256, 256, 0, stream>>>(ws + o_base, dtab, VTb);
    }

    // ---- score pass (raw S in log2 domain + chunk max) ----
    {
        dim3 g(8, 144, 1);
        attn_score<<<g, 256, 0, stream>>>(Qb, Kb, SRb, ws + o_mc);
    }
    // ---- GEMM2 with fused exp2 (denominator via ones column) ----
    {
        dim3 g(8, 144, 1);
        gemm2_kernel<<<g, 256, 0, stream>>>(VTb, SRb, ws + o_mc, Zb);
    }
    combine_stats<<<(4 * HW + 255) / 256, 256, 0, stream>>>(ws + o_mc, Zb, ws + o_fac);
    // ---- weighted chunk reduction ----
    {
        int n = 4 * JD * HW / 8;
        chunk_reduce<<<(n + 255) / 256, 256, 0, stream>>>(Zb, ws + o_fac, Zrb);
    }
    final_kernel<<<(4 * 50 * HW + 255) / 256, 256, 0, stream>>>(Zrb, x, out);
}

// Round 10
// 498.571 us; speedup vs baseline: 1.1281x; 1.1281x over previous
//
#include <hip/hip_runtime.h>
#include <hip/hip_bf16.h>
#include <hip/hip_fp16.h>
#include <math.h>

// ---------------------------------------------------------------------------
// RFDN panet attention, MI355X.  Round 10:
//   - round 9's swizzled gemm2 (bank conflicts = 0, verified) but WITHOUT the
//     __launch_bounds__(256,4) VGPR cap that caused scratch spills
//     (r9 counters: WRITE_SIZE 37->273 MB = spill traffic).
// ---------------------------------------------------------------------------

#define L_TOT 7470
#define L_PAD 7680   // 64 * 120, 4 chunks of 1920
#define NCHUNK 4
#define CHUNK_TILES 30   // 64-key tiles per chunk
#define KD    256    // padded 225
#define JD    512    // padded 450 = 50*3*3
#define HW    2304   // 48*48

typedef unsigned short u16;
typedef __attribute__((ext_vector_type(8))) short bf16x8;
typedef __attribute__((ext_vector_type(4))) float f32x4;

__device__ inline u16 f2b(float f) {
    __hip_bfloat16 h = __float2bfloat16(f);
    return __builtin_bit_cast(u16, h);
}
__device__ inline float b2f(u16 u) {
    __hip_bfloat16 h = __builtin_bit_cast(__hip_bfloat16, u);
    return __bfloat162float(h);
}
__device__ inline u16 f2h(float f) {
    __half h = __float2half(f);
    return __builtin_bit_cast(u16, h);
}
__device__ inline float h2f(u16 u) {
    __half h = __builtin_bit_cast(__half, u);
    return __half2float(h);
}

__constant__ int c_hs[5]   = {48, 43, 38, 33, 28};
__constant__ int c_loff[6] = {0, 2304, 4153, 5597, 6686, 7470};

#define GLOAD16(g, l) __builtin_amdgcn_global_load_lds(                          \
        (__attribute__((address_space(1))) const void*)(g),                      \
        (__attribute__((address_space(3))) void*)(l), 16, 0, 0)

// --------------------------- prep: resize weights + decode table -----------
__global__ void prep_kernel(float* __restrict__ wmall, int* __restrict__ dtab) {
    int r = blockIdx.x * 256 + threadIdx.x;
    if (r < 142) {
        int sizes[4] = {43, 38, 33, 28};
        int si = 0, i = r, woffs = 0;
        for (si = 0; si < 4; ++si) {
            if (i < sizes[si]) break;
            i -= sizes[si];
            woffs += sizes[si] * 48;
        }
        int osz = sizes[si];
        float inv_scale = 48.0f / (float)osz;
        float kscale = inv_scale;
        float sample_f = ((float)i + 0.5f) * inv_scale - 0.5f;
        float w[48];
        float tot = 0.f;
        for (int j = 0; j < 48; ++j) {
            float t = fabsf(sample_f - (float)j) / kscale;
            float v;
            if (t >= 2.f)       v = 0.f;
            else if (t >= 1.f)  v = ((-0.5f * t + 2.5f) * t - 4.f) * t + 2.f;
            else                v = ((1.5f * t - 2.5f) * t) * t + 1.f;
            w[j] = v;
            tot += v;
        }
        float invt = 1.f / tot;
        for (int j = 0; j < 48; ++j) wmall[woffs + i * 48 + j] = w[j] * invt;
    }
    if (r < L_PAD) {
        int v;
        if (r >= L_TOT) v = (int)0x80000000u;
        else {
            int si = 0;
#pragma unroll
            for (int s = 0; s < 4; ++s)
                if (r >= c_loff[s + 1]) si = s + 1;
            int pos = r - c_loff[si];
            int hs = c_hs[si];
            int ly = pos / hs, lx = pos % hs;
            v = si | (ly << 4) | (lx << 10);
        }
        dtab[r] = v;
    }
}

// --------------------------- fused resizes ---------------------------------
__global__ void resize_h_all(const float* __restrict__ in, const float* __restrict__ wm,
                             float* __restrict__ t1, float* __restrict__ t2,
                             float* __restrict__ t3, float* __restrict__ t4) {
    int idx = blockIdx.x * 256 + threadIdx.x;
    int rem = idx, osz, woffm;
    float* tmp;
    if (rem < 200 * 43 * 48) { osz = 43; tmp = t1; woffm = 0; }
    else {
        rem -= 200 * 43 * 48;
        if (rem < 200 * 38 * 48) { osz = 38; tmp = t2; woffm = 43 * 48; }
        else {
            rem -= 200 * 38 * 48;
            if (rem < 200 * 33 * 48) { osz = 33; tmp = t3; woffm = (43 + 38) * 48; }
            else {
                rem -= 200 * 33 * 48;
                if (rem >= 200 * 28 * 48) return;
                osz = 28; tmp = t4; woffm = (43 + 38 + 33) * 48;
            }
        }
    }
    int xi = rem % 48;
    int t = rem / 48;
    int yo = t % osz;
    int bc = t / osz;
    const float* wr = wm + (size_t)(woffm + yo * 48);
    const float* ip = in + (size_t)bc * 2304 + xi;
    float s = 0.f;
#pragma unroll
    for (int yi = 0; yi < 48; ++yi) s += wr[yi] * ip[yi * 48];
    tmp[rem] = s;
}

__global__ void resize_w_all(const float* __restrict__ t1, const float* __restrict__ t2,
                             const float* __restrict__ t3, const float* __restrict__ t4,
                             const float* __restrict__ wm,
                             float* __restrict__ r1, float* __restrict__ r2,
                             float* __restrict__ r3, float* __restrict__ r4) {
    int idx = blockIdx.x * 256 + threadIdx.x;
    int rem = idx, osz, woffm;
    const float* tmp;
    float* outp;
    if (rem < 200 * 43 * 43) { osz = 43; tmp = t1; outp = r1; woffm = 0; }
    else {
        rem -= 200 * 43 * 43;
        if (rem < 200 * 38 * 38) { osz = 38; tmp = t2; outp = r2; woffm = 43 * 48; }
        else {
            rem -= 200 * 38 * 38;
            if (rem < 200 * 33 * 33) { osz = 33; tmp = t3; outp = r3; woffm = (43 + 38) * 48; }
            else {
                rem -= 200 * 33 * 33;
                if (rem >= 200 * 28 * 28) return;
                osz = 28; tmp = t4; outp = r4; woffm = (43 + 38 + 33) * 48;
            }
        }
    }
    int xo = rem % osz;
    int t = rem / osz;
    int yo = t % osz;
    int bc = t / osz;
    const float* wr = wm + (size_t)(woffm + xo * 48);
    const float* ip = tmp + ((size_t)bc * osz + yo) * 48;
    float s = 0.f;
#pragma unroll
    for (int xi = 0; xi < 48; ++xi) s += wr[xi] * ip[xi];
    outp[rem] = s;
}

// ------------- fused 1x1 convs (asm+match all scales, base at scale 0) -----
__global__ void conv_all(const float* __restrict__ x,
                         const float* __restrict__ r1, const float* __restrict__ r2,
                         const float* __restrict__ r3, const float* __restrict__ r4,
                         const float* __restrict__ w_asm, const float* __restrict__ b_asm,
                         const float* __restrict__ a_asm,
                         const float* __restrict__ w_match, const float* __restrict__ b_match,
                         const float* __restrict__ a_match,
                         const float* __restrict__ w_base, const float* __restrict__ b_base,
                         const float* __restrict__ a_base,
                         float* __restrict__ base_out, float* __restrict__ refm_out,
                         float* __restrict__ mb_out) {
    int idx = blockIdx.x * 256 + threadIdx.x;
    int rem = idx, P, loffv, NCO;
    const float* in;
    if (rem < 400 * 2304) { P = 2304; in = x; loffv = 0; NCO = 100; }
    else {
        rem -= 400 * 2304;
        if (rem < 300 * 1849) { P = 1849; in = r1; loffv = 2304; NCO = 75; }
        else {
            rem -= 300 * 1849;
            if (rem < 300 * 1444) { P = 1444; in = r2; loffv = 4153; NCO = 75; }
            else {
                rem -= 300 * 1444;
                if (rem < 300 * 1089) { P = 1089; in = r3; loffv = 5597; NCO = 75; }
                else {
                    rem -= 300 * 1089;
                    if (rem >= 300 * 784) return;
                    P = 784; in = r4; loffv = 6686; NCO = 75;
                }
            }
        }
    }
    int p = rem % P;
    int t = rem / P;
    int co = t % NCO;
    int b = t / NCO;
    const float* ip = in + (size_t)b * 50 * P + p;
    const float* wr;
    float bias, av;
    float* outp;
    if (co < 50) {
        wr = w_asm + co * 50; bias = b_asm[co]; av = a_asm[0];
        outp = base_out + (size_t)200 * loffv + ((size_t)(b * 50 + co)) * P + p;
    } else if (co < 75) {
        int cm = co - 50;
        wr = w_match + cm * 50; bias = b_match[cm]; av = a_match[0];
        outp = refm_out + (size_t)100 * loffv + ((size_t)(b * 25 + cm)) * P + p;
    } else {
        int cm = co - 75;
        wr = w_base + cm * 50; bias = b_base[cm]; av = a_base[0];
        outp = mb_out + ((size_t)(b * 25 + cm)) * P + p;
    }
    float s = bias;
#pragma unroll
    for (int ci = 0; ci < 50; ++ci) s += wr[ci] * ip[(size_t)ci * P];
    *outp = (s >= 0.f) ? s : av * s;
}

// --------------------------- builders (dtab-based) -------------------------
__global__ void q_build(const float* __restrict__ mb, u16* __restrict__ Q) {
    int idx = blockIdx.x * 256 + threadIdx.x;
    if (idx >= 4 * HW * 25) return;
    int c = idx % 25;
    int t = idx / 25;
    int p = t % HW;
    int b = t / HW;
    int y = p / 48, xx = p % 48;
    const float* rc = mb + (size_t)(b * 25 + c) * HW;
    u16 ov[9];
#pragma unroll
    for (int ky = 0; ky < 3; ++ky)
#pragma unroll
        for (int kx = 0; kx < 3; ++kx) {
            int yy = y + ky - 1, xv = xx + kx - 1;
            float v = (yy >= 0 && yy < 48 && xv >= 0 && xv < 48) ? rc[yy * 48 + xv] : 0.f;
            ov[ky * 3 + kx] = f2b(v);
        }
    u16* dst = Q + (size_t)(b * HW + p) * KD + c * 9;
#pragma unroll
    for (int r = 0; r < 9; ++r) dst[r] = ov[r];
    if (c == 24) {
        u16* z = dst + 9;
#pragma unroll
        for (int i = 0; i < 31; ++i) z[i] = 0;
    }
}

// norms carry SM_SCALE * log2(e) so scores live in the exp2 domain
__global__ void norms_kernel(const float* __restrict__ refm_all, const int* __restrict__ dtab,
                             float* __restrict__ norms) {
    int idx = blockIdx.x * 256 + threadIdx.x;
    if (idx >= 4 * L_PAD) return;
    int l = idx % L_PAD;
    int b = idx / L_PAD;
    int d = dtab[l];
    if (d < 0) return;
    int si = d & 15, ly = (d >> 4) & 63, lx = (d >> 10) & 63;
    int hs = c_hs[si], P = hs * hs;
    const float* rb = refm_all + (size_t)100 * c_loff[si] + (size_t)(b * 25) * P;
    float ss = 0.f;
    for (int c = 0; c < 25; ++c) {
        const float* rc = rb + (size_t)c * P;
#pragma unroll
        for (int ky = 0; ky < 3; ++ky)
#pragma unroll
            for (int kx = 0; kx < 3; ++kx) {
                int yy = ly + ky - 1, xv = lx + kx - 1;
                if (yy >= 0 && yy < hs && xv >= 0 && xv < hs) {
                    float v = rc[yy * hs + xv];
                    ss += v * v;
                }
            }
    }
    norms[(size_t)b * L_PAD + l] = 10.0f * 1.44269504f / fmaxf(sqrtf(ss), 1e-4f);
}

__global__ void kt_build(const float* __restrict__ refm_all, const int* __restrict__ dtab,
                         const float* __restrict__ norms, u16* __restrict__ K) {
    int idx = blockIdx.x * 256 + threadIdx.x;
    if (idx >= 4 * L_PAD * 25) return;
    int c = idx % 25;
    int t = idx / 25;
    int l = t % L_PAD;
    int b = t / L_PAD;
    u16 ov[9] = {0, 0, 0, 0, 0, 0, 0, 0, 0};
    int d = dtab[l];
    if (d >= 0) {
        int si = d & 15, ly = (d >> 4) & 63, lx = (d >> 10) & 63;
        int hs = c_hs[si], P = hs * hs;
        float nrm = norms[(size_t)b * L_PAD + l];
        const float* rc = refm_all + (size_t)100 * c_loff[si] + (size_t)(b * 25 + c) * P;
#pragma unroll
        for (int ky = 0; ky < 3; ++ky)
#pragma unroll
            for (int kx = 0; kx < 3; ++kx) {
                int yy = ly + ky - 1, xv = lx + kx - 1;
                if (yy >= 0 && yy < hs && xv >= 0 && xv < hs)
                    ov[ky * 3 + kx] = f2b(rc[yy * hs + xv] * nrm);
            }
    }
    u16* dst = K + (size_t)(b * L_PAD + l) * KD + c * 9;
#pragma unroll
    for (int r = 0; r < 9; ++r) dst[r] = ov[r];
    if (c == 24) {
        u16* z = dst + 9;
#pragma unroll
        for (int i = 0; i < 31; ++i) z[i] = 0;
    }
}

// VT: thread per (b,j,l8); j==450 is the all-ones denominator column.
__global__ void v_build(const float* __restrict__ base_all, const int* __restrict__ dtab,
                        u16* __restrict__ VT) {
    int idx = blockIdx.x * 256 + threadIdx.x;
    if (idx >= 4 * JD * (L_PAD / 8)) return;
    int l8 = idx % (L_PAD / 8);
    int t = idx / (L_PAD / 8);
    int j = t % JD;
    int b = t / JD;
    int l0 = l8 * 8;
    bf16x8 ov = (bf16x8){0, 0, 0, 0, 0, 0, 0, 0};
    if (j < 450) {
        int c = j / 9, r = j % 9, ky = r / 3, kx = r % 3;
#pragma unroll
        for (int u = 0; u < 8; ++u) {
            int d = dtab[l0 + u];
            float v = 0.f;
            if (d >= 0) {
                int si = d & 15, ly = (d >> 4) & 63, lx = (d >> 10) & 63;
                int hs = c_hs[si], P = hs * hs;
                int yy = ly + ky - 1, xv = lx + kx - 1;
                if (yy >= 0 && yy < hs && xv >= 0 && xv < hs)
                    v = base_all[(size_t)200 * c_loff[si] + (size_t)(b * 50 + c) * P + yy * hs + xv];
            }
            ov[u] = (short)f2b(v);
        }
    } else if (j == 450) {
        const u16 one = f2b(1.0f);
#pragma unroll
        for (int u = 0; u < 8; ++u)
            ov[u] = (short)(dtab[l0 + u] >= 0 ? one : 0);
    }
    *(bf16x8*)&VT[(size_t)(b * JD + j) * L_PAD + l0] = ov;
}

// --------------------------- score pass (single sweep) ---------------------
__global__ __launch_bounds__(256, 4) void attn_score(
    const u16* __restrict__ Qg, const u16* __restrict__ Kg,
    u16* __restrict__ SRg, float* __restrict__ mC) {
    __shared__ u16 smem[64 * KD];         // 32 KB
    __shared__ float sm_m[2][32];
    const int bx = blockIdx.x, by = blockIdx.y;
    const int mt = by % 72, zq = by / 72;
    const int z16 = bx + 8 * zq;
    const int b = z16 >> 2, chunk = z16 & 3;
    const int bm = mt * 32;
    const u16* Q = Qg + (size_t)b * HW * KD;
    const u16* K = Kg + (size_t)b * L_PAD * KD;
    u16* SR = SRg + (size_t)b * HW * L_PAD;
    const int tid = threadIdx.x, lane = tid & 63, wid = tid >> 6;
    const int wr = wid >> 1, wc = wid & 1;
    const int l15 = lane & 15, l16 = lane >> 4, l7 = lane & 7;
    const int r_lo = lane >> 5;
    const int u_dst = lane & 31;

    {
        const u16* qrow = Q + (size_t)(bm + wid * 8 + r_lo) * KD;
        u16* qdst = smem + (size_t)(wid * 8) * KD;
#pragma unroll
        for (int q = 0; q < 4; ++q) {
            int sw = (u_dst ^ ((q * 2 + r_lo) & 7)) * 8;
            GLOAD16(qrow + (size_t)(q * 2) * KD + sw, qdst + (q * 2) * KD);
        }
    }
    __syncthreads();
    bf16x8 qf[8];
#pragma unroll
    for (int k = 0; k < 8; ++k)
        qf[k] = *(const bf16x8*)&smem[(size_t)(wr * 16 + l15) * KD + (((k * 4 + l16) ^ l7) * 8)];
    __syncthreads();

    float mrun[4] = {-3e38f, -3e38f, -3e38f, -3e38f};
    const int t0 = chunk * CHUNK_TILES;

    for (int t = t0; t < t0 + CHUNK_TILES; ++t) {
        {
            const u16* krow = K + (size_t)(t * 64 + wid * 16 + r_lo) * KD;
            u16* kdst = smem + (size_t)(wid * 16) * KD;
#pragma unroll
            for (int q = 0; q < 8; ++q) {
                int sw = (u_dst ^ ((q * 2 + r_lo) & 7)) * 8;
                GLOAD16(krow + (size_t)(q * 2) * KD + sw, kdst + (q * 2) * KD);
            }
        }
        __syncthreads();
        f32x4 acc[2];
#pragma unroll
        for (int n = 0; n < 2; ++n) acc[n] = (f32x4){0.f, 0.f, 0.f, 0.f};
#pragma unroll
        for (int k = 0; k < 8; ++k) {
            bf16x8 bfr[2];
#pragma unroll
            for (int n = 0; n < 2; ++n)
                bfr[n] = *(const bf16x8*)&smem[(size_t)(wc * 32 + n * 16 + l15) * KD
                                               + (((k * 4 + l16) ^ l7) * 8)];
#pragma unroll
            for (int n = 0; n < 2; ++n)
                acc[n] = __builtin_amdgcn_mfma_f32_16x16x32_bf16(qf[k], bfr[n], acc[n], 0, 0, 0);
        }
        const int col0 = t * 64 + wc * 32 + l15;
        const int row0 = bm + wr * 16 + l16 * 4;
#pragma unroll
        for (int n = 0; n < 2; ++n) {
            const int col = col0 + n * 16;
            const bool vld = col < L_TOT;
#pragma unroll
            for (int r = 0; r < 4; ++r) {
                float s = acc[n][r];
                if (vld) mrun[r] = fmaxf(mrun[r], s);
                SR[(size_t)(row0 + r) * L_PAD + col] = vld ? f2h(s) : (u16)0xFC00;
            }
        }
        __syncthreads();
    }

#pragma unroll
    for (int r = 0; r < 4; ++r) {
        float mv = mrun[r];
#pragma unroll
        for (int st = 1; st <= 8; st <<= 1)
            mv = fmaxf(mv, __shfl_xor(mv, st));
        mrun[r] = mv;
    }
    if (l15 == 0) {
#pragma unroll
        for (int r = 0; r < 4; ++r)
            sm_m[wc][wr * 16 + l16 * 4 + r] = mrun[r];
    }
    __syncthreads();
    if (wc == 0 && l15 == 0) {
#pragma unroll
        for (int r = 0; r < 4; ++r) {
            int row = wr * 16 + l16 * 4 + r;
            mC[(size_t)(chunk * 4 + b) * HW + bm + row] = fmaxf(sm_m[0][row], sm_m[1][row]);
        }
    }
}

// --------------------------- GEMM2 with fused exp2, swizzled LDS -----------
// Zt_z[j][pp] = sum_l VT[j][l] * exp2(SR[pp][l] - mC[pp,chunk])
__global__ __launch_bounds__(256) void gemm2_kernel(
    const u16* __restrict__ VT0, const u16* __restrict__ SR0,
    const float* __restrict__ mC, u16* __restrict__ C0) {
    __shared__ u16 As[128 * 64];
    __shared__ u16 Bs[128 * 64];
    const int bx = blockIdx.x, by = blockIdx.y;
    const int within = by % 72, zq = by / 72;
    const int mt = within & 3, nt = within >> 2;
    const int z = bx + 8 * zq;
    const int batch = z >> 2, chunk = z & 3;
    const u16* A = VT0 + (size_t)batch * JD * L_PAD + chunk * (CHUNK_TILES * 64);
    const u16* B = SR0 + (size_t)batch * HW * L_PAD + chunk * (CHUNK_TILES * 64);
    u16* C = C0 + (size_t)z * JD * HW;
    const int bm = mt * 128, bn = nt * 128;
    const int tid = threadIdx.x, lane = tid & 63, wid = tid >> 6;
    const int wr = wid >> 1, wc = wid & 1;
    const int srow = lane >> 3;           // 0..7
    const int u8 = lane & 7;              // 16B unit
    const int l15 = lane & 15, l16 = lane >> 4;
    const int swu = (u8 ^ srow) * 8;      // swizzled element offset within row

    float mrow[4];
    {
        const float* mp = mC + (size_t)(chunk * 4 + batch) * HW;
#pragma unroll
        for (int q = 0; q < 4; ++q)
            mrow[q] = mp[bn + wid * 32 + srow + q * 8];
    }

    f32x4 acc[4][4];
#pragma unroll
    for (int i = 0; i < 4; ++i)
#pragma unroll
        for (int j = 0; j < 4; ++j) acc[i][j] = (f32x4){0.f, 0.f, 0.f, 0.f};

    const u16* aGrow = A + (size_t)(bm + wid * 32 + srow) * L_PAD;   // col added per tile
    const u16* bG = B + (size_t)(bn + wid * 32 + srow) * L_PAD + u8 * 8;
    u16* aL = As + wid * 32 * 64;

    union U8 { uint4 v; u16 h[8]; };
    uint4 bv[4];
#pragma unroll
    for (int q = 0; q < 4; ++q)
        bv[q] = *(const uint4*)(bG + (size_t)q * 8 * L_PAD);
    bG += 64;

    for (int t = 0; t < CHUNK_TILES; ++t) {
        // A stage: linear LDS dest, pre-swizzled global source column
#pragma unroll
        for (int q = 0; q < 4; ++q)
            GLOAD16(aGrow + (size_t)q * 8 * L_PAD + t * 64 + swu, aL + q * 8 * 64);
        uint4 bnext[4];
        if (t < CHUNK_TILES - 1) {
#pragma unroll
            for (int q = 0; q < 4; ++q)
                bnext[q] = *(const uint4*)(bG + (size_t)q * 8 * L_PAD);
            bG += 64;
        }
        // exp2-process current B tile -> swizzled LDS write
#pragma unroll
        for (int q = 0; q < 4; ++q) {
            U8 uu; uu.v = bv[q];
            bf16x8 ob;
#pragma unroll
            for (int u = 0; u < 8; ++u) {
                float e = exp2f(h2f(uu.h[u]) - mrow[q]);
                ob[u] = (short)f2b(e);
            }
            *(bf16x8*)&Bs[(size_t)(wid * 32 + srow + q * 8) * 64 + swu] = ob;
        }
        __syncthreads();
#pragma unroll
        for (int kc = 0; kc < 64; kc += 32) {
            bf16x8 af[4], bf[4];
#pragma unroll
            for (int m = 0; m < 4; ++m)
                af[m] = *(const bf16x8*)&As[(wr * 64 + m * 16 + l15) * 64
                                            + (((kc >> 3) + l16) ^ (l15 & 7)) * 8];
#pragma unroll
            for (int n = 0; n < 4; ++n)
                bf[n] = *(const bf16x8*)&Bs[(wc * 64 + n * 16 + l15) * 64
                                            + (((kc >> 3) + l16) ^ (l15 & 7)) * 8];
#pragma unroll
            for (int m = 0; m < 4; ++m)
#pragma unroll
                for (int n = 0; n < 4; ++n)
                    acc[m][n] = __builtin_amdgcn_mfma_f32_16x16x32_bf16(af[m], bf[n], acc[m][n], 0, 0, 0);
        }
        __syncthreads();
#pragma unroll
        for (int q = 0; q < 4; ++q) bv[q] = bnext[q];
    }
    const int crow0 = bm + wr * 64 + (lane >> 4) * 4;
    const int ccol = bn + wc * 64 + l15;
#pragma unroll
    for (int m = 0; m < 4; ++m)
#pragma unroll
        for (int n = 0; n < 4; ++n)
#pragma unroll
            for (int r = 0; r < 4; ++r)
                C[(size_t)(crow0 + m * 16 + r) * HW + ccol + n * 16] = f2b(acc[m][n][r]);
}

// --------------------------- combine chunk stats (after GEMM2) -------------
__global__ void combine_stats(const float* __restrict__ mC, const u16* __restrict__ Zt,
                              float* __restrict__ fac) {
    int idx = blockIdx.x * 256 + threadIdx.x;
    if (idx >= 4 * HW) return;
    int b = idx / HW, p = idx % HW;
    float m[NCHUNK], d[NCHUNK];
#pragma unroll
    for (int c = 0; c < NCHUNK; ++c) {
        m[c] = mC[(size_t)(c * 4 + b) * HW + p];
        d[c] = b2f(Zt[((size_t)(b * 4 + c) * JD + 450) * HW + p]);
    }
    float mf = m[0];
#pragma unroll
    for (int c = 1; c < NCHUNK; ++c) mf = fmaxf(mf, m[c]);
    float w[NCHUNK], df = 0.f;
#pragma unroll
    for (int c = 0; c < NCHUNK; ++c) { w[c] = exp2f(m[c] - mf); df += d[c] * w[c]; }
    float inv = 1.0f / df;
#pragma unroll
    for (int c = 0; c < NCHUNK; ++c) fac[(size_t)(c * 4 + b) * HW + p] = w[c] * inv;
}

// --------------------------- chunk reduce (weighted sum over chunks) -------
__global__ void chunk_reduce(const u16* __restrict__ Zt, const float* __restrict__ fac,
                             u16* __restrict__ Zred) {
    int idx = blockIdx.x * 256 + threadIdx.x;
    int total = 4 * JD * HW / 8;
    if (idx >= total) return;
    int e8 = idx * 8;
    int pp = e8 % HW;
    int row = e8 / HW;          // row = b*JD + j
    int b = row / JD;
    float s[8] = {};
#pragma unroll
    for (int ch = 0; ch < NCHUNK; ++ch) {
        const float* fp = fac + (size_t)(ch * 4 + b) * HW + pp;
        bf16x8 zv = *(const bf16x8*)&Zt[((size_t)(b * 4 + ch) * JD + (row % JD)) * HW + pp];
#pragma unroll
        for (int u = 0; u < 8; ++u)
            s[u] += fp[u] * b2f((u16)zv[u]);
    }
    bf16x8 o;
#pragma unroll
    for (int u = 0; u < 8; ++u) o[u] = (short)f2b(s[u]);
    *(bf16x8*)&Zred[(size_t)row * HW + pp] = o;
}

// --------------------------- final: 9-tap gather + residual ----------------
__global__ void final_kernel(const u16* __restrict__ Zred, const float* __restrict__ x,
                             float* __restrict__ out) {
    int idx = blockIdx.x * 256 + threadIdx.x;
    if (idx >= 4 * 50 * HW) return;
    int p = idx % HW;
    int t = idx / HW;
    int c = t % 50;
    int b = t / 50;
    int y = p / 48, xx = p % 48;
    const u16* Zb = Zred + (size_t)b * JD * HW;
    float s = 0.f;
#pragma unroll
    for (int ky = 0; ky < 3; ++ky) {
        int yy = y + ky - 1;
        if (yy < 0 || yy >= 48) continue;
#pragma unroll
        for (int kx = 0; kx < 3; ++kx) {
            int xv = xx + kx - 1;
            if (xv < 0 || xv >= 48) continue;
            int pp = yy * 48 + xv;
            int j = c * 9 + (2 - ky) * 3 + (2 - kx);
            s += b2f(Zb[(size_t)j * HW + pp]);
        }
    }
    size_t o = ((size_t)b * 50 + c) * HW + p;
    out[o] = x[o] + 0.25f * s;
}

// ---------------------------------------------------------------------------
extern "C" void kernel_launch(void* const* d_in, const int* in_sizes, int n_in,
                              void* d_out, int out_size, void* d_ws, size_t ws_size,
                              hipStream_t stream) {
    const float* x       = (const float*)d_in[0];
    const float* w_base  = (const float*)d_in[1];
    const float* b_base  = (const float*)d_in[2];
    const float* a_base  = (const float*)d_in[3];
    const float* w_match = (const float*)d_in[4];
    const float* b_match = (const float*)d_in[5];
    const float* a_match = (const float*)d_in[6];
    const float* w_asm   = (const float*)d_in[7];
    const float* b_asm   = (const float*)d_in[8];
    const float* a_asm   = (const float*)d_in[9];
    float* out = (float*)d_out;
    float* ws = (float*)d_ws;
    (void)in_sizes; (void)n_in; (void)out_size; (void)ws_size;

    // ---- builder scratch (aliases head of SR; dead before attn_score) ----
    size_t off = 0;
    auto alloc = [&](size_t n) { size_t o = off; off += (n + 63) & ~(size_t)63; return o; };
    size_t o_wm = alloc(142 * 48);
    size_t o_dtab = alloc(L_PAD);
    size_t o_t1 = alloc((size_t)200 * 43 * 48);
    size_t o_t2 = alloc((size_t)200 * 38 * 48);
    size_t o_t3 = alloc((size_t)200 * 33 * 48);
    size_t o_t4 = alloc((size_t)200 * 28 * 48);
    size_t o_r1 = alloc((size_t)200 * 43 * 43);
    size_t o_r2 = alloc((size_t)200 * 38 * 38);
    size_t o_r3 = alloc((size_t)200 * 33 * 33);
    size_t o_r4 = alloc((size_t)200 * 28 * 28);
    size_t o_base = alloc((size_t)200 * L_TOT);
    size_t o_refm = alloc((size_t)100 * L_TOT);
    size_t o_mb = alloc((size_t)100 * HW);
    size_t o_norms = alloc((size_t)4 * L_PAD);

    // ---- persistent layout (floats) ----
    size_t o_SR = 0;                                      // fp16 [4][HW][L_PAD]
    size_t o_Q = (size_t)4 * HW * L_PAD / 2;
    size_t o_K = o_Q + (size_t)4 * HW * KD / 2;
    size_t o_VT = o_K + (size_t)4 * L_PAD * KD / 2;
    size_t o_Z = o_VT + (size_t)4 * JD * L_PAD / 2;       // bf16 [16][JD][HW]
    size_t o_mc = o_Z + (size_t)16 * JD * HW / 2;         // f32 [16][HW]
    size_t o_fac = o_mc + (size_t)16 * HW;                // f32 [16][HW]
    size_t o_zred = o_fac + (size_t)16 * HW;              // bf16 [4][JD][HW]

    u16* Qb = (u16*)(ws + o_Q);
    u16* Kb = (u16*)(ws + o_K);
    u16* VTb = (u16*)(ws + o_VT);
    u16* SRb = (u16*)(ws + o_SR);
    u16* Zb = (u16*)(ws + o_Z);
    u16* Zrb = (u16*)(ws + o_zred);
    int* dtab = (int*)(ws + o_dtab);

    // ---- prep ----
    prep_kernel<<<(L_PAD + 255) / 256, 256, 0, stream>>>(ws + o_wm, dtab);
    // ---- resizes ----
    {
        int n = 200 * 48 * (43 + 38 + 33 + 28);
        resize_h_all<<<(n + 255) / 256, 256, 0, stream>>>(x, ws + o_wm, ws + o_t1,
                                                          ws + o_t2, ws + o_t3, ws + o_t4);
    }
    {
        int n = 200 * (43 * 43 + 38 * 38 + 33 * 33 + 28 * 28);
        resize_w_all<<<(n + 255) / 256, 256, 0, stream>>>(ws + o_t1, ws + o_t2, ws + o_t3,
                                                          ws + o_t4, ws + o_wm, ws + o_r1,
                                                          ws + o_r2, ws + o_r3, ws + o_r4);
    }
    // ---- convs ----
    {
        int n = 400 * 2304 + 300 * (1849 + 1444 + 1089 + 784);
        conv_all<<<(n + 255) / 256, 256, 0, stream>>>(
            x, ws + o_r1, ws + o_r2, ws + o_r3, ws + o_r4,
            w_asm, b_asm, a_asm, w_match, b_match, a_match, w_base, b_base, a_base,
            ws + o_base, ws + o_refm, ws + o_mb);
    }
    // ---- operand builders ----
    {
        int n = 4 * HW * 25;
        q_build<<<(n + 255) / 256, 256, 0, stream>>>(ws + o_mb, Qb);
    }
    {
        int n = 4 * L_PAD;
        norms_kernel<<<(n + 255) / 256, 256, 0, stream>>>(ws + o_refm, dtab, ws + o_norms);
    }
    {
        int n = 4 * L_PAD * 25;
        kt_build<<<(n + 255) / 256, 256, 0, stream>>>(ws + o_refm, dtab, ws + o_norms, Kb);
    }
    {
        int n = 4 * JD * (L_PAD / 8);
        v_build<<<(n + 255) / 256, 256, 0, stream>>>(ws + o_base, dtab, VTb);
    }

    // ---- score pass (raw S in log2 domain + chunk max) ----
    {
        dim3 g(8, 144, 1);
        attn_score<<<g, 256, 0, stream>>>(Qb, Kb, SRb, ws + o_mc);
    }
    // ---- GEMM2 with fused exp2 (denominator via ones column) ----
    {
        dim3 g(8, 144, 1);
        gemm2_kernel<<<g, 256, 0, stream>>>(VTb, SRb, ws + o_mc, Zb);
    }
    combine_stats<<<(4 * HW + 255) / 256, 256, 0, stream>>>(ws + o_mc, Zb, ws + o_fac);
    // ---- weighted chunk reduction ----
    {
        int n = 4 * JD * HW / 8;
        chunk_reduce<<<(n + 255) / 256, 256, 0, stream>>>(Zb, ws + o_fac, Zrb);
    }
    final_kernel<<<(4 * 50 * HW + 255) / 256, 256, 0, stream>>>(Zrb, x, out);
}

// Round 14
// 467.033 us; speedup vs baseline: 1.2043x; 1.0675x over previous
//
#include <hip/hip_runtime.h>
#include <hip/hip_bf16.h>
#include <hip/hip_fp16.h>
#include <math.h>

// ---------------------------------------------------------------------------
// RFDN panet attention, MI355X.  Round 12 design (3rd submit; two prior
// attempts hit GPU acquisition timeouts and never ran):
//   - attn_score phase 3: in-place exp2(S - m_chunk) rewrite of its own
//     L2-hot strip (fp16 S -> bf16 P).  Exp happens ONCE (was 4x in gemm2).
//   - gemm2: PURE bf16 GEMM, both operands via global_load_lds with
//     source-swizzle (0 bank conflicts, r10-proven), no VALU exp, no staging.
//   - combine_stats / chunk_reduce / final unchanged from r10.
// ---------------------------------------------------------------------------

#define L_TOT 7470
#define L_PAD 7680   // 64 * 120, 4 chunks of 1920
#define NCHUNK 4
#define CHUNK_TILES 30   // 64-key tiles per chunk
#define KD    256    // padded 225
#define JD    512    // padded 450 = 50*3*3
#define HW    2304   // 48*48

typedef unsigned short u16;
typedef __attribute__((ext_vector_type(8))) short bf16x8;
typedef __attribute__((ext_vector_type(4))) float f32x4;

__device__ inline u16 f2b(float f) {
    __hip_bfloat16 h = __float2bfloat16(f);
    return __builtin_bit_cast(u16, h);
}
__device__ inline float b2f(u16 u) {
    __hip_bfloat16 h = __builtin_bit_cast(__hip_bfloat16, u);
    return __bfloat162float(h);
}
__device__ inline u16 f2h(float f) {
    __half h = __float2half(f);
    return __builtin_bit_cast(u16, h);
}
__device__ inline float h2f(u16 u) {
    __half h = __builtin_bit_cast(__half, u);
    return __half2float(h);
}

__constant__ int c_hs[5]   = {48, 43, 38, 33, 28};
__constant__ int c_loff[6] = {0, 2304, 4153, 5597, 6686, 7470};

#define GLOAD16(g, l) __builtin_amdgcn_global_load_lds(                          \
        (__attribute__((address_space(1))) const void*)(g),                      \
        (__attribute__((address_space(3))) void*)(l), 16, 0, 0)

// --------------------------- prep: resize weights + decode table -----------
__global__ void prep_kernel(float* __restrict__ wmall, int* __restrict__ dtab) {
    int r = blockIdx.x * 256 + threadIdx.x;
    if (r < 142) {
        int sizes[4] = {43, 38, 33, 28};
        int si = 0, i = r, woffs = 0;
        for (si = 0; si < 4; ++si) {
            if (i < sizes[si]) break;
            i -= sizes[si];
            woffs += sizes[si] * 48;
        }
        int osz = sizes[si];
        float inv_scale = 48.0f / (float)osz;
        float kscale = inv_scale;
        float sample_f = ((float)i + 0.5f) * inv_scale - 0.5f;
        float w[48];
        float tot = 0.f;
        for (int j = 0; j < 48; ++j) {
            float t = fabsf(sample_f - (float)j) / kscale;
            float v;
            if (t >= 2.f)       v = 0.f;
            else if (t >= 1.f)  v = ((-0.5f * t + 2.5f) * t - 4.f) * t + 2.f;
            else                v = ((1.5f * t - 2.5f) * t) * t + 1.f;
            w[j] = v;
            tot += v;
        }
        float invt = 1.f / tot;
        for (int j = 0; j < 48; ++j) wmall[woffs + i * 48 + j] = w[j] * invt;
    }
    if (r < L_PAD) {
        int v;
        if (r >= L_TOT) v = (int)0x80000000u;
        else {
            int si = 0;
#pragma unroll
            for (int s = 0; s < 4; ++s)
                if (r >= c_loff[s + 1]) si = s + 1;
            int pos = r - c_loff[si];
            int hs = c_hs[si];
            int ly = pos / hs, lx = pos % hs;
            v = si | (ly << 4) | (lx << 10);
        }
        dtab[r] = v;
    }
}

// --------------------------- fused resizes ---------------------------------
__global__ void resize_h_all(const float* __restrict__ in, const float* __restrict__ wm,
                             float* __restrict__ t1, float* __restrict__ t2,
                             float* __restrict__ t3, float* __restrict__ t4) {
    int idx = blockIdx.x * 256 + threadIdx.x;
    int rem = idx, osz, woffm;
    float* tmp;
    if (rem < 200 * 43 * 48) { osz = 43; tmp = t1; woffm = 0; }
    else {
        rem -= 200 * 43 * 48;
        if (rem < 200 * 38 * 48) { osz = 38; tmp = t2; woffm = 43 * 48; }
        else {
            rem -= 200 * 38 * 48;
            if (rem < 200 * 33 * 48) { osz = 33; tmp = t3; woffm = (43 + 38) * 48; }
            else {
                rem -= 200 * 33 * 48;
                if (rem >= 200 * 28 * 48) return;
                osz = 28; tmp = t4; woffm = (43 + 38 + 33) * 48;
            }
        }
    }
    int xi = rem % 48;
    int t = rem / 48;
    int yo = t % osz;
    int bc = t / osz;
    const float* wr = wm + (size_t)(woffm + yo * 48);
    const float* ip = in + (size_t)bc * 2304 + xi;
    float s = 0.f;
#pragma unroll
    for (int yi = 0; yi < 48; ++yi) s += wr[yi] * ip[yi * 48];
    tmp[rem] = s;
}

__global__ void resize_w_all(const float* __restrict__ t1, const float* __restrict__ t2,
                             const float* __restrict__ t3, const float* __restrict__ t4,
                             const float* __restrict__ wm,
                             float* __restrict__ r1, float* __restrict__ r2,
                             float* __restrict__ r3, float* __restrict__ r4) {
    int idx = blockIdx.x * 256 + threadIdx.x;
    int rem = idx, osz, woffm;
    const float* tmp;
    float* outp;
    if (rem < 200 * 43 * 43) { osz = 43; tmp = t1; outp = r1; woffm = 0; }
    else {
        rem -= 200 * 43 * 43;
        if (rem < 200 * 38 * 38) { osz = 38; tmp = t2; outp = r2; woffm = 43 * 48; }
        else {
            rem -= 200 * 38 * 38;
            if (rem < 200 * 33 * 33) { osz = 33; tmp = t3; outp = r3; woffm = (43 + 38) * 48; }
            else {
                rem -= 200 * 33 * 33;
                if (rem >= 200 * 28 * 28) return;
                osz = 28; tmp = t4; outp = r4; woffm = (43 + 38 + 33) * 48;
            }
        }
    }
    int xo = rem % osz;
    int t = rem / osz;
    int yo = t % osz;
    int bc = t / osz;
    const float* wr = wm + (size_t)(woffm + xo * 48);
    const float* ip = tmp + ((size_t)bc * osz + yo) * 48;
    float s = 0.f;
#pragma unroll
    for (int xi = 0; xi < 48; ++xi) s += wr[xi] * ip[xi];
    outp[rem] = s;
}

// ------------- fused 1x1 convs (asm+match all scales, base at scale 0) -----
__global__ void conv_all(const float* __restrict__ x,
                         const float* __restrict__ r1, const float* __restrict__ r2,
                         const float* __restrict__ r3, const float* __restrict__ r4,
                         const float* __restrict__ w_asm, const float* __restrict__ b_asm,
                         const float* __restrict__ a_asm,
                         const float* __restrict__ w_match, const float* __restrict__ b_match,
                         const float* __restrict__ a_match,
                         const float* __restrict__ w_base, const float* __restrict__ b_base,
                         const float* __restrict__ a_base,
                         float* __restrict__ base_out, float* __restrict__ refm_out,
                         float* __restrict__ mb_out) {
    int idx = blockIdx.x * 256 + threadIdx.x;
    int rem = idx, P, loffv, NCO;
    const float* in;
    if (rem < 400 * 2304) { P = 2304; in = x; loffv = 0; NCO = 100; }
    else {
        rem -= 400 * 2304;
        if (rem < 300 * 1849) { P = 1849; in = r1; loffv = 2304; NCO = 75; }
        else {
            rem -= 300 * 1849;
            if (rem < 300 * 1444) { P = 1444; in = r2; loffv = 4153; NCO = 75; }
            else {
                rem -= 300 * 1444;
                if (rem < 300 * 1089) { P = 1089; in = r3; loffv = 5597; NCO = 75; }
                else {
                    rem -= 300 * 1089;
                    if (rem >= 300 * 784) return;
                    P = 784; in = r4; loffv = 6686; NCO = 75;
                }
            }
        }
    }
    int p = rem % P;
    int t = rem / P;
    int co = t % NCO;
    int b = t / NCO;
    const float* ip = in + (size_t)b * 50 * P + p;
    const float* wr;
    float bias, av;
    float* outp;
    if (co < 50) {
        wr = w_asm + co * 50; bias = b_asm[co]; av = a_asm[0];
        outp = base_out + (size_t)200 * loffv + ((size_t)(b * 50 + co)) * P + p;
    } else if (co < 75) {
        int cm = co - 50;
        wr = w_match + cm * 50; bias = b_match[cm]; av = a_match[0];
        outp = refm_out + (size_t)100 * loffv + ((size_t)(b * 25 + cm)) * P + p;
    } else {
        int cm = co - 75;
        wr = w_base + cm * 50; bias = b_base[cm]; av = a_base[0];
        outp = mb_out + ((size_t)(b * 25 + cm)) * P + p;
    }
    float s = bias;
#pragma unroll
    for (int ci = 0; ci < 50; ++ci) s += wr[ci] * ip[(size_t)ci * P];
    *outp = (s >= 0.f) ? s : av * s;
}

// --------------------------- builders (dtab-based) -------------------------
__global__ void q_build(const float* __restrict__ mb, u16* __restrict__ Q) {
    int idx = blockIdx.x * 256 + threadIdx.x;
    if (idx >= 4 * HW * 25) return;
    int c = idx % 25;
    int t = idx / 25;
    int p = t % HW;
    int b = t / HW;
    int y = p / 48, xx = p % 48;
    const float* rc = mb + (size_t)(b * 25 + c) * HW;
    u16 ov[9];
#pragma unroll
    for (int ky = 0; ky < 3; ++ky)
#pragma unroll
        for (int kx = 0; kx < 3; ++kx) {
            int yy = y + ky - 1, xv = xx + kx - 1;
            float v = (yy >= 0 && yy < 48 && xv >= 0 && xv < 48) ? rc[yy * 48 + xv] : 0.f;
            ov[ky * 3 + kx] = f2b(v);
        }
    u16* dst = Q + (size_t)(b * HW + p) * KD + c * 9;
#pragma unroll
    for (int r = 0; r < 9; ++r) dst[r] = ov[r];
    if (c == 24) {
        u16* z = dst + 9;
#pragma unroll
        for (int i = 0; i < 31; ++i) z[i] = 0;
    }
}

// norms carry SM_SCALE * log2(e) so scores live in the exp2 domain
__global__ void norms_kernel(const float* __restrict__ refm_all, const int* __restrict__ dtab,
                             float* __restrict__ norms) {
    int idx = blockIdx.x * 256 + threadIdx.x;
    if (idx >= 4 * L_PAD) return;
    int l = idx % L_PAD;
    int b = idx / L_PAD;
    int d = dtab[l];
    if (d < 0) return;
    int si = d & 15, ly = (d >> 4) & 63, lx = (d >> 10) & 63;
    int hs = c_hs[si], P = hs * hs;
    const float* rb = refm_all + (size_t)100 * c_loff[si] + (size_t)(b * 25) * P;
    float ss = 0.f;
    for (int c = 0; c < 25; ++c) {
        const float* rc = rb + (size_t)c * P;
#pragma unroll
        for (int ky = 0; ky < 3; ++ky)
#pragma unroll
            for (int kx = 0; kx < 3; ++kx) {
                int yy = ly + ky - 1, xv = lx + kx - 1;
                if (yy >= 0 && yy < hs && xv >= 0 && xv < hs) {
                    float v = rc[yy * hs + xv];
                    ss += v * v;
                }
            }
    }
    norms[(size_t)b * L_PAD + l] = 10.0f * 1.44269504f / fmaxf(sqrtf(ss), 1e-4f);
}

__global__ void kt_build(const float* __restrict__ refm_all, const int* __restrict__ dtab,
                         const float* __restrict__ norms, u16* __restrict__ K) {
    int idx = blockIdx.x * 256 + threadIdx.x;
    if (idx >= 4 * L_PAD * 25) return;
    int c = idx % 25;
    int t = idx / 25;
    int l = t % L_PAD;
    int b = t / L_PAD;
    u16 ov[9] = {0, 0, 0, 0, 0, 0, 0, 0, 0};
    int d = dtab[l];
    if (d >= 0) {
        int si = d & 15, ly = (d >> 4) & 63, lx = (d >> 10) & 63;
        int hs = c_hs[si], P = hs * hs;
        float nrm = norms[(size_t)b * L_PAD + l];
        const float* rc = refm_all + (size_t)100 * c_loff[si] + (size_t)(b * 25 + c) * P;
#pragma unroll
        for (int ky = 0; ky < 3; ++ky)
#pragma unroll
            for (int kx = 0; kx < 3; ++kx) {
                int yy = ly + ky - 1, xv = lx + kx - 1;
                if (yy >= 0 && yy < hs && xv >= 0 && xv < hs)
                    ov[ky * 3 + kx] = f2b(rc[yy * hs + xv] * nrm);
            }
    }
    u16* dst = K + (size_t)(b * L_PAD + l) * KD + c * 9;
#pragma unroll
    for (int r = 0; r < 9; ++r) dst[r] = ov[r];
    if (c == 24) {
        u16* z = dst + 9;
#pragma unroll
        for (int i = 0; i < 31; ++i) z[i] = 0;
    }
}

// VT (bf16): thread per (b,j,l8); j==450 is the all-ones denominator column.
__global__ void v_build(const float* __restrict__ base_all, const int* __restrict__ dtab,
                        u16* __restrict__ VT) {
    int idx = blockIdx.x * 256 + threadIdx.x;
    if (idx >= 4 * JD * (L_PAD / 8)) return;
    int l8 = idx % (L_PAD / 8);
    int t = idx / (L_PAD / 8);
    int j = t % JD;
    int b = t / JD;
    int l0 = l8 * 8;
    bf16x8 ov = (bf16x8){0, 0, 0, 0, 0, 0, 0, 0};
    if (j < 450) {
        int c = j / 9, r = j % 9, ky = r / 3, kx = r % 3;
#pragma unroll
        for (int u = 0; u < 8; ++u) {
            int d = dtab[l0 + u];
            float v = 0.f;
            if (d >= 0) {
                int si = d & 15, ly = (d >> 4) & 63, lx = (d >> 10) & 63;
                int hs = c_hs[si], P = hs * hs;
                int yy = ly + ky - 1, xv = lx + kx - 1;
                if (yy >= 0 && yy < hs && xv >= 0 && xv < hs)
                    v = base_all[(size_t)200 * c_loff[si] + (size_t)(b * 50 + c) * P + yy * hs + xv];
            }
            ov[u] = (short)f2b(v);
        }
    } else if (j == 450) {
        const u16 one = f2b(1.0f);
#pragma unroll
        for (int u = 0; u < 8; ++u)
            ov[u] = (short)(dtab[l0 + u] >= 0 ? one : 0);
    }
    *(bf16x8*)&VT[(size_t)(b * JD + j) * L_PAD + l0] = ov;
}

// --------------- score pass + in-place exp (3 phases) ----------------------
// Phase 1: S = QK^T (fp16, raw) for this block's 32x1920 strip + running max.
// Phase 2: reduce row max (chunk max) -> sm_m[0][row], write mC.
// Phase 3: re-read own strip (L2-hot), write P = exp2(S - m_chunk) as bf16
//          in place.  Downstream per-chunk combine unchanged (r10 semantics).
__global__ __launch_bounds__(256, 4) void attn_score(
    const u16* __restrict__ Qg, const u16* __restrict__ Kg,
    u16* __restrict__ SRg, float* __restrict__ mC) {
    __shared__ u16 smem[64 * KD];         // 32 KB
    __shared__ float sm_m[2][32];
    const int bx = blockIdx.x, by = blockIdx.y;
    const int mt = by % 72, zq = by / 72;
    const int z16 = bx + 8 * zq;
    const int b = z16 >> 2, chunk = z16 & 3;
    const int bm = mt * 32;
    const u16* Q = Qg + (size_t)b * HW * KD;
    const u16* K = Kg + (size_t)b * L_PAD * KD;
    u16* SR = SRg + (size_t)b * HW * L_PAD;
    const int tid = threadIdx.x, lane = tid & 63, wid = tid >> 6;
    const int wr = wid >> 1, wc = wid & 1;
    const int l15 = lane & 15, l16 = lane >> 4, l7 = lane & 7;
    const int r_lo = lane >> 5;
    const int u_dst = lane & 31;

    {
        const u16* qrow = Q + (size_t)(bm + wid * 8 + r_lo) * KD;
        u16* qdst = smem + (size_t)(wid * 8) * KD;
#pragma unroll
        for (int q = 0; q < 4; ++q) {
            int sw = (u_dst ^ ((q * 2 + r_lo) & 7)) * 8;
            GLOAD16(qrow + (size_t)(q * 2) * KD + sw, qdst + (q * 2) * KD);
        }
    }
    __syncthreads();
    bf16x8 qf[8];
#pragma unroll
    for (int k = 0; k < 8; ++k)
        qf[k] = *(const bf16x8*)&smem[(size_t)(wr * 16 + l15) * KD + (((k * 4 + l16) ^ l7) * 8)];
    __syncthreads();

    float mrun[4] = {-3e38f, -3e38f, -3e38f, -3e38f};
    const int t0 = chunk * CHUNK_TILES;

    for (int t = t0; t < t0 + CHUNK_TILES; ++t) {
        {
            const u16* krow = K + (size_t)(t * 64 + wid * 16 + r_lo) * KD;
            u16* kdst = smem + (size_t)(wid * 16) * KD;
#pragma unroll
            for (int q = 0; q < 8; ++q) {
                int sw = (u_dst ^ ((q * 2 + r_lo) & 7)) * 8;
                GLOAD16(krow + (size_t)(q * 2) * KD + sw, kdst + (q * 2) * KD);
            }
        }
        __syncthreads();
        f32x4 acc[2];
#pragma unroll
        for (int n = 0; n < 2; ++n) acc[n] = (f32x4){0.f, 0.f, 0.f, 0.f};
#pragma unroll
        for (int k = 0; k < 8; ++k) {
            bf16x8 bfr[2];
#pragma unroll
            for (int n = 0; n < 2; ++n)
                bfr[n] = *(const bf16x8*)&smem[(size_t)(wc * 32 + n * 16 + l15) * KD
                                               + (((k * 4 + l16) ^ l7) * 8)];
#pragma unroll
            for (int n = 0; n < 2; ++n)
                acc[n] = __builtin_amdgcn_mfma_f32_16x16x32_bf16(qf[k], bfr[n], acc[n], 0, 0, 0);
        }
        const int col0 = t * 64 + wc * 32 + l15;
        const int row0 = bm + wr * 16 + l16 * 4;
#pragma unroll
        for (int n = 0; n < 2; ++n) {
            const int col = col0 + n * 16;
            const bool vld = col < L_TOT;
#pragma unroll
            for (int r = 0; r < 4; ++r) {
                float s = acc[n][r];
                if (vld) mrun[r] = fmaxf(mrun[r], s);
                SR[(size_t)(row0 + r) * L_PAD + col] = vld ? f2h(s) : (u16)0xFC00;
            }
        }
        __syncthreads();
    }

    // ---- phase 2: chunk row max -> sm_m[0][row] + mC ----
#pragma unroll
    for (int r = 0; r < 4; ++r) {
        float mv = mrun[r];
#pragma unroll
        for (int st = 1; st <= 8; st <<= 1)
            mv = fmaxf(mv, __shfl_xor(mv, st));
        mrun[r] = mv;
    }
    if (l15 == 0) {
#pragma unroll
        for (int r = 0; r < 4; ++r)
            sm_m[wc][wr * 16 + l16 * 4 + r] = mrun[r];
    }
    __syncthreads();
    if (wc == 0 && l15 == 0) {
#pragma unroll
        for (int r = 0; r < 4; ++r) {
            int row = wr * 16 + l16 * 4 + r;
            float mm = fmaxf(sm_m[0][row], sm_m[1][row]);
            sm_m[0][row] = mm;
            mC[(size_t)(chunk * 4 + b) * HW + bm + row] = mm;
        }
    }
    __syncthreads();

    // ---- phase 3: in-place exp2(S - m_chunk), fp16 S -> bf16 P ----
    const int cb = t0 * 64;
#pragma unroll 2
    for (int i = 0; i < 30; ++i) {
        int id = i * 256 + tid;            // 0..7679 = 32 rows x 240 col-octets
        int row = id / 240;
        int c8 = id - row * 240;
        u16* ptr = SR + (size_t)(bm + row) * L_PAD + cb + c8 * 8;
        float m = sm_m[0][row];
        bf16x8 iv = *(const bf16x8*)ptr;
        bf16x8 o;
#pragma unroll
        for (int u = 0; u < 8; ++u)
            o[u] = (short)f2b(exp2f(h2f((u16)iv[u]) - m));
        *(bf16x8*)ptr = o;
    }
}

// ------------------ GEMM2: pure bf16, both operands via GLOAD16 ------------
// Zt_z[j][pp] = sum_l VT[j][l] * P[pp][l]   (P = exp'd S, bf16, in SR buffer)
__global__ __launch_bounds__(256) void gemm2_kernel(
    const u16* __restrict__ VT0, const u16* __restrict__ P0,
    u16* __restrict__ C0) {
    __shared__ u16 As[128 * 64];
    __shared__ u16 Bs[128 * 64];
    const int bx = blockIdx.x, by = blockIdx.y;
    const int within = by % 72, zq = by / 72;
    const int mt = within & 3, nt = within >> 2;
    const int z = bx + 8 * zq;
    const int batch = z >> 2, chunk = z & 3;
    const u16* A = VT0 + (size_t)batch * JD * L_PAD + chunk * (CHUNK_TILES * 64);
    const u16* B = P0 + (size_t)batch * HW * L_PAD + chunk * (CHUNK_TILES * 64);
    u16* C = C0 + (size_t)z * JD * HW;
    const int bm = mt * 128, bn = nt * 128;
    const int tid = threadIdx.x, lane = tid & 63, wid = tid >> 6;
    const int wr = wid >> 1, wc = wid & 1;
    const int srow = lane >> 3;           // 0..7
    const int u8 = lane & 7;              // 16B unit
    const int l15 = lane & 15, l16 = lane >> 4;
    const int swu = (u8 ^ srow) * 8;      // swizzled element offset within row

    f32x4 acc[4][4];
#pragma unroll
    for (int i = 0; i < 4; ++i)
#pragma unroll
        for (int j = 0; j < 4; ++j) acc[i][j] = (f32x4){0.f, 0.f, 0.f, 0.f};

    const u16* aGrow = A + (size_t)(bm + wid * 32 + srow) * L_PAD;
    const u16* bGrow = B + (size_t)(bn + wid * 32 + srow) * L_PAD;
    u16* aL = As + wid * 32 * 64;
    u16* bL = Bs + wid * 32 * 64;

    for (int t = 0; t < CHUNK_TILES; ++t) {
#pragma unroll
        for (int q = 0; q < 4; ++q) {
            GLOAD16(aGrow + (size_t)q * 8 * L_PAD + t * 64 + swu, aL + q * 8 * 64);
            GLOAD16(bGrow + (size_t)q * 8 * L_PAD + t * 64 + swu, bL + q * 8 * 64);
        }
        __syncthreads();
#pragma unroll
        for (int kc = 0; kc < 64; kc += 32) {
            const int fs = (((kc >> 3) + l16) ^ (l15 & 7)) * 8;
            bf16x8 af[4], bf[4];
#pragma unroll
            for (int m = 0; m < 4; ++m)
                af[m] = *(const bf16x8*)&As[(wr * 64 + m * 16 + l15) * 64 + fs];
#pragma unroll
            for (int n = 0; n < 4; ++n)
                bf[n] = *(const bf16x8*)&Bs[(wc * 64 + n * 16 + l15) * 64 + fs];
#pragma unroll
            for (int m = 0; m < 4; ++m)
#pragma unroll
                for (int n = 0; n < 4; ++n)
                    acc[m][n] = __builtin_amdgcn_mfma_f32_16x16x32_bf16(af[m], bf[n], acc[m][n], 0, 0, 0);
        }
        __syncthreads();
    }
    const int crow0 = bm + wr * 64 + (lane >> 4) * 4;
    const int ccol = bn + wc * 64 + l15;
#pragma unroll
    for (int m = 0; m < 4; ++m)
#pragma unroll
        for (int n = 0; n < 4; ++n)
#pragma unroll
            for (int r = 0; r < 4; ++r)
                C[(size_t)(crow0 + m * 16 + r) * HW + ccol + n * 16] = f2b(acc[m][n][r]);
}

// --------------------------- combine chunk stats (after GEMM2) -------------
__global__ void combine_stats(const float* __restrict__ mC, const u16* __restrict__ Zt,
                              float* __restrict__ fac) {
    int idx = blockIdx.x * 256 + threadIdx.x;
    if (idx >= 4 * HW) return;
    int b = idx / HW, p = idx % HW;
    float m[NCHUNK], d[NCHUNK];
#pragma unroll
    for (int c = 0; c < NCHUNK; ++c) {
        m[c] = mC[(size_t)(c * 4 + b) * HW + p];
        d[c] = b2f(Zt[((size_t)(b * 4 + c) * JD + 450) * HW + p]);
    }
    float mf = m[0];
#pragma unroll
    for (int c = 1; c < NCHUNK; ++c) mf = fmaxf(mf, m[c]);
    float w[NCHUNK], df = 0.f;
#pragma unroll
    for (int c = 0; c < NCHUNK; ++c) { w[c] = exp2f(m[c] - mf); df += d[c] * w[c]; }
    float inv = 1.0f / df;
#pragma unroll
    for (int c = 0; c < NCHUNK; ++c) fac[(size_t)(c * 4 + b) * HW + p] = w[c] * inv;
}

// --------------------------- chunk reduce (weighted sum over chunks) -------
__global__ void chunk_reduce(const u16* __restrict__ Zt, const float* __restrict__ fac,
                             u16* __restrict__ Zred) {
    int idx = blockIdx.x * 256 + threadIdx.x;
    int total = 4 * JD * HW / 8;
    if (idx >= total) return;
    int e8 = idx * 8;
    int pp = e8 % HW;
    int row = e8 / HW;          // row = b*JD + j
    int b = row / JD;
    float s[8] = {};
#pragma unroll
    for (int ch = 0; ch < NCHUNK; ++ch) {
        const float* fp = fac + (size_t)(ch * 4 + b) * HW + pp;
        bf16x8 zv = *(const bf16x8*)&Zt[((size_t)(b * 4 + ch) * JD + (row % JD)) * HW + pp];
#pragma unroll
        for (int u = 0; u < 8; ++u)
            s[u] += fp[u] * b2f((u16)zv[u]);
    }
    bf16x8 o;
#pragma unroll
    for (int u = 0; u < 8; ++u) o[u] = (short)f2b(s[u]);
    *(bf16x8*)&Zred[(size_t)row * HW + pp] = o;
}

// --------------------------- final: 9-tap gather + residual ----------------
__global__ void final_kernel(const u16* __restrict__ Zred, const float* __restrict__ x,
                             float* __restrict__ out) {
    int idx = blockIdx.x * 256 + threadIdx.x;
    if (idx >= 4 * 50 * HW) return;
    int p = idx % HW;
    int t = idx / HW;
    int c = t % 50;
    int b = t / 50;
    int y = p / 48, xx = p % 48;
    const u16* Zb = Zred + (size_t)b * JD * HW;
    float s = 0.f;
#pragma unroll
    for (int ky = 0; ky < 3; ++ky) {
        int yy = y + ky - 1;
        if (yy < 0 || yy >= 48) continue;
#pragma unroll
        for (int kx = 0; kx < 3; ++kx) {
            int xv = xx + kx - 1;
            if (xv < 0 || xv >= 48) continue;
            int pp = yy * 48 + xv;
            int j = c * 9 + (2 - ky) * 3 + (2 - kx);
            s += b2f(Zb[(size_t)j * HW + pp]);
        }
    }
    size_t o = ((size_t)b * 50 + c) * HW + p;
    out[o] = x[o] + 0.25f * s;
}

// ---------------------------------------------------------------------------
extern "C" void kernel_launch(void* const* d_in, const int* in_sizes, int n_in,
                              void* d_out, int out_size, void* d_ws, size_t ws_size,
                              hipStream_t stream) {
    const float* x       = (const float*)d_in[0];
    const float* w_base  = (const float*)d_in[1];
    const float* b_base  = (const float*)d_in[2];
    const float* a_base  = (const float*)d_in[3];
    const float* w_match = (const float*)d_in[4];
    const float* b_match = (const float*)d_in[5];
    const float* a_match = (const float*)d_in[6];
    const float* w_asm   = (const float*)d_in[7];
    const float* b_asm   = (const float*)d_in[8];
    const float* a_asm   = (const float*)d_in[9];
    float* out = (float*)d_out;
    float* ws = (float*)d_ws;
    (void)in_sizes; (void)n_in; (void)out_size; (void)ws_size;

    // ---- builder scratch (aliases head of SR; dead before attn_score) ----
    size_t off = 0;
    auto alloc = [&](size_t n) { size_t o = off; off += (n + 63) & ~(size_t)63; return o; };
    size_t o_wm = alloc(142 * 48);
    size_t o_dtab = alloc(L_PAD);
    size_t o_t1 = alloc((size_t)200 * 43 * 48);
    size_t o_t2 = alloc((size_t)200 * 38 * 48);
    size_t o_t3 = alloc((size_t)200 * 33 * 48);
    size_t o_t4 = alloc((size_t)200 * 28 * 48);
    size_t o_r1 = alloc((size_t)200 * 43 * 43);
    size_t o_r2 = alloc((size_t)200 * 38 * 38);
    size_t o_r3 = alloc((size_t)200 * 33 * 33);
    size_t o_r4 = alloc((size_t)200 * 28 * 28);
    size_t o_base = alloc((size_t)200 * L_TOT);
    size_t o_refm = alloc((size_t)100 * L_TOT);
    size_t o_mb = alloc((size_t)100 * HW);
    size_t o_norms = alloc((size_t)4 * L_PAD);

    // ---- persistent layout (floats) ----
    size_t o_SR = 0;                                      // fp16 S / bf16 P
    size_t o_Q = (size_t)4 * HW * L_PAD / 2;
    size_t o_K = o_Q + (size_t)4 * HW * KD / 2;
    size_t o_VT = o_K + (size_t)4 * L_PAD * KD / 2;
    size_t o_Z = o_VT + (size_t)4 * JD * L_PAD / 2;       // bf16 [16][JD][HW]
    size_t o_mc = o_Z + (size_t)16 * JD * HW / 2;         // f32 [16][HW]
    size_t o_fac = o_mc + (size_t)16 * HW;                // f32 [16][HW]
    size_t o_zred = o_fac + (size_t)16 * HW;              // bf16 [4][JD][HW]

    u16* Qb = (u16*)(ws + o_Q);
    u16* Kb = (u16*)(ws + o_K);
    u16* VTb = (u16*)(ws + o_VT);
    u16* SRb = (u16*)(ws + o_SR);
    u16* Zb = (u16*)(ws + o_Z);
    u16* Zrb = (u16*)(ws + o_zred);
    int* dtab = (int*)(ws + o_dtab);

    // ---- prep ----
    prep_kernel<<<(L_PAD + 255) / 256, 256, 0, stream>>>(ws + o_wm, dtab);
    // ---- resizes ----
    {
        int n = 200 * 48 * (43 + 38 + 33 + 28);
        resize_h_all<<<(n + 255) / 256, 256, 0, stream>>>(x, ws + o_wm, ws + o_t1,
                                                          ws + o_t2, ws + o_t3, ws + o_t4);
    }
    {
        int n = 200 * (43 * 43 + 38 * 38 + 33 * 33 + 28 * 28);
        resize_w_all<<<(n + 255) / 256, 256, 0, stream>>>(ws + o_t1, ws + o_t2, ws + o_t3,
                                                          ws + o_t4, ws + o_wm, ws + o_r1,
                                                          ws + o_r2, ws + o_r3, ws + o_r4);
    }
    // ---- convs ----
    {
        int n = 400 * 2304 + 300 * (1849 + 1444 + 1089 + 784);
        conv_all<<<(n + 255) / 256, 256, 0, stream>>>(
            x, ws + o_r1, ws + o_r2, ws + o_r3, ws + o_r4,
            w_asm, b_asm, a_asm, w_match, b_match, a_match, w_base, b_base, a_base,
            ws + o_base, ws + o_refm, ws + o_mb);
    }
    // ---- operand builders ----
    {
        int n = 4 * HW * 25;
        q_build<<<(n + 255) / 256, 256, 0, stream>>>(ws + o_mb, Qb);
    }
    {
        int n = 4 * L_PAD;
        norms_kernel<<<(n + 255) / 256, 256, 0, stream>>>(ws + o_refm, dtab, ws + o_norms);
    }
    {
        int n = 4 * L_PAD * 25;
        kt_build<<<(n + 255) / 256, 256, 0, stream>>>(ws + o_refm, dtab, ws + o_norms, Kb);
    }
    {
        int n = 4 * JD * (L_PAD / 8);
        v_build<<<(n + 255) / 256, 256, 0, stream>>>(ws + o_base, dtab, VTb);
    }

    // ---- score + in-place exp (writes P bf16 + chunk max) ----
    {
        dim3 g(8, 144, 1);
        attn_score<<<g, 256, 0, stream>>>(Qb, Kb, SRb, ws + o_mc);
    }
    // ---- GEMM2 pure bf16 (denominator via ones column) ----
    {
        dim3 g(8, 144, 1);
        gemm2_kernel<<<g, 256, 0, stream>>>(VTb, SRb, Zb);
    }
    combine_stats<<<(4 * HW + 255) / 256, 256, 0, stream>>>(ws + o_mc, Zb, ws + o_fac);
    // ---- weighted chunk reduction ----
    {
        int n = 4 * JD * HW / 8;
        chunk_reduce<<<(n + 255) / 256, 256, 0, stream>>>(Zb, ws + o_fac, Zrb);
    }
    final_kernel<<<(4 * 50 * HW + 255) / 256, 256, 0, stream>>>(Zrb, x, out);
}